// Round 8
// baseline (246.247 us; speedup 1.0000x reference)
//
#include <hip/hip_runtime.h>
#include <math.h>

// Problem constants (B=4, T=2048, C=1024, H=16, hs=64)
#define B_   4
#define T_   2048
#define C_   1024
#define H_   16
#define HS   64
#define HALF 32
#define QKV_N (3 * C_)      // 3072
#define M_    (B_ * T_)     // 8192

using bf16x8 = __attribute__((ext_vector_type(8))) short;
using f32x4  = __attribute__((ext_vector_type(4))) float;
using f32x16 = __attribute__((ext_vector_type(16))) float;

__device__ __forceinline__ unsigned short f2bf(float f) {
    unsigned u = __builtin_bit_cast(unsigned, f);
    u = (u + 0x7FFFu + ((u >> 16) & 1u)) >> 16;
    return (unsigned short)u;
}
__device__ __forceinline__ float bf2f(unsigned short b) {
    return __builtin_bit_cast(float, (unsigned)b << 16);
}
__device__ __forceinline__ unsigned cvtpk_bf16(float lo, float hi_) {
    unsigned r;
    asm("v_cvt_pk_bf16_f32 %0, %1, %2" : "=v"(r) : "v"(lo), "v"(hi_));
    return r;
}
__device__ __forceinline__ void gload16(const void* g, void* l) {
    __builtin_amdgcn_global_load_lds(
        (const __attribute__((address_space(1))) unsigned int*)g,
        (__attribute__((address_space(3))) unsigned int*)l, 16, 0, 0);
}
#define WAIT_VMCNT_8() asm volatile("s_waitcnt vmcnt(8)" ::: "memory")
#define WAIT_VMCNT_0() asm volatile("s_waitcnt vmcnt(0)" ::: "memory")

// ---------------------------------------------------------------------------
// fp32 -> bf16 cast, 8 elements/thread.
// ---------------------------------------------------------------------------
__global__ __launch_bounds__(256) void cast_bf16_kernel(
    const float* __restrict__ in, unsigned short* __restrict__ out)
{
    const size_t i = ((size_t)blockIdx.x * 256 + threadIdx.x) * 8;
    const float4 a = *reinterpret_cast<const float4*>(&in[i]);
    const float4 b = *reinterpret_cast<const float4*>(&in[i + 4]);
    bf16x8 v;
    v[0] = f2bf(a.x); v[1] = f2bf(a.y); v[2] = f2bf(a.z); v[3] = f2bf(a.w);
    v[4] = f2bf(b.x); v[5] = f2bf(b.y); v[6] = f2bf(b.z); v[7] = f2bf(b.w);
    *reinterpret_cast<bf16x8*>(&out[i]) = v;
}

// ---------------------------------------------------------------------------
// Transpose + cast: W[K][N] fp32 -> Wt[N][K] bf16. 32x32 tiles.
// ---------------------------------------------------------------------------
__global__ __launch_bounds__(256) void transpose_cast_kernel(
    const float* __restrict__ W, unsigned short* __restrict__ Wt, int K, int N)
{
    __shared__ float tile[32][33];
    const int r = threadIdx.x / 32;      // 0..7
    const int c = threadIdx.x % 32;
    const int k0 = blockIdx.y * 32;
    const int n0 = blockIdx.x * 32;
    #pragma unroll
    for (int it = 0; it < 4; ++it)
        tile[r + it * 8][c] = W[(size_t)(k0 + r + it * 8) * N + n0 + c];
    __syncthreads();
    #pragma unroll
    for (int it = 0; it < 4; ++it)
        Wt[(size_t)(n0 + r + it * 8) * K + k0 + c] = f2bf(tile[c][r + it * 8]);
}

// ---------------------------------------------------------------------------
// RoPE table: tab[t*HALF + i] = (sin, cos) of t * 10000^(-i/HALF)
// ---------------------------------------------------------------------------
__global__ __launch_bounds__(256) void rope_table_kernel(float2* __restrict__ tab)
{
    const int idx = blockIdx.x * 256 + threadIdx.x;   // 0 .. T_*HALF-1
    const int t = idx / HALF;
    const int i = idx % HALF;
    const float theta = powf(10000.0f, -(float)i / (float)HALF);
    const float ang = (float)t * theta;
    float sn, cs;
    sincosf(ang, &sn, &cs);
    tab[idx] = make_float2(sn, cs);
}

// ---------------------------------------------------------------------------
// V^T precompute: qkv v-slice [b*T+t][2C + h*64 + d] -> vt[((b*H+h)*64+d)*T + t]
// ---------------------------------------------------------------------------
__global__ __launch_bounds__(256) void vtrans_kernel(
    const unsigned short* __restrict__ qkv, unsigned short* __restrict__ vt)
{
    __shared__ unsigned short tile[64][72];
    const int tt = blockIdx.x & 31;
    const int h  = (blockIdx.x >> 5) & 15;
    const int b  = blockIdx.x >> 9;
    const int tid = threadIdx.x;
    const int r  = tid >> 2;          // 0..63
    const int c0 = (tid & 3) * 16;    // 0,16,32,48
    {
        const unsigned short* g =
            &qkv[(size_t)(b * T_ + tt * 64 + r) * QKV_N + 2 * C_ + h * HS + c0];
        const bf16x8 v0 = *reinterpret_cast<const bf16x8*>(g);
        const bf16x8 v1 = *reinterpret_cast<const bf16x8*>(g + 8);
        *reinterpret_cast<bf16x8*>(&tile[r][c0])     = v0;
        *reinterpret_cast<bf16x8*>(&tile[r][c0 + 8]) = v1;
    }
    __syncthreads();
    bf16x8 o0, o1;
    #pragma unroll
    for (int u = 0; u < 8; ++u) o0[u] = tile[c0 + u][r];
    #pragma unroll
    for (int u = 0; u < 8; ++u) o1[u] = tile[c0 + 8 + u][r];
    unsigned short* g = &vt[((size_t)((b * H_ + h) * HS + r)) * T_ + tt * 64 + c0];
    *reinterpret_cast<bf16x8*>(g)     = o0;
    *reinterpret_cast<bf16x8*>(g + 8) = o1;
}

// ---------------------------------------------------------------------------
// GEMM v7: C[M,N] = A[M,K] @ Bt[N,K]^T + bias (+fused RoPE on cols<2048).
// BM=BN=256, BK=64. 512 threads = 8 waves (2M x 4N), per-wave 128x64
// (24 ds_read_b128 : 64 MFMA per K-tile). 2-buffer LDS (128 KB).
// SCHEDULE (the round's experiment): per K-tile
//   stage(t+1 -> alt)  [8 loads issued FIRST]
//   24 ds_read + 64 MFMA, NO scheduling pins (compiler interleaves lgkmcnt)
//   vmcnt(0)           [waits loads issued a FULL TILE ago -> ~zero stall]
//   one s_barrier      [WAR distance to overwrite = 2 barriers]
// XOR-swizzled LDS slots (slot ^= row&7) via pre-swizzled global source.
// ---------------------------------------------------------------------------
template <bool BF16OUT, bool ROPE>
__global__ __launch_bounds__(512, 1) void gemm_v7_kernel(
    const unsigned short* __restrict__ A, const unsigned short* __restrict__ Bt,
    const float* __restrict__ bias, const float2* __restrict__ tab,
    void* __restrict__ Cout, int M, int N, int K, int nbx)
{
    __shared__ unsigned short As[2][256 * 64];
    __shared__ unsigned short Bs[2][256 * 64];

    const int tid  = threadIdx.x;
    const int lane = tid & 63;
    const int wave = tid >> 6;        // 0..7
    const int wr   = wave >> 2;       // 0..1 : M half (128 rows)
    const int wc   = wave & 3;        // 0..3 : N quarter (64 cols)
    const int l15  = lane & 15;
    const int l4   = lane >> 4;

    // XCD swizzle (grid % 8 == 0 at both call sites)
    int bid = blockIdx.x;
    const int cpx = gridDim.x >> 3;
    bid = (bid & 7) * cpx + (bid >> 3);
    const int by = bid / nbx, bx = bid % nbx;
    const int row0 = by * 256, col0 = bx * 256;

    // staging: thread covers rows p*64 + (tid>>3), 16B slot tid&7 (dest linear)
    const int srow  = tid >> 3;
    const int sslot = tid & 7;

    auto stage = [&](int buf, int t) {          // 8 loads / thread
        const int k0 = t * 64;
        #pragma unroll
        for (int p = 0; p < 4; ++p) {
            const int r  = p * 64 + srow;
            const int sk = (sslot ^ (r & 7)) * 8;
            gload16(&A[(size_t)(row0 + r) * K + k0 + sk],
                    &As[buf][(p * 512 + tid) * 8]);
        }
        #pragma unroll
        for (int p = 0; p < 4; ++p) {
            const int r  = p * 64 + srow;
            const int sk = (sslot ^ (r & 7)) * 8;
            gload16(&Bt[(size_t)(col0 + r) * K + k0 + sk],
                    &Bs[buf][(p * 512 + tid) * 8]);
        }
    };

    f32x4 acc[8][4] = {};
    const int nt = K >> 6;            // 16

    // prologue
    stage(0, 0);
    WAIT_VMCNT_0();
    __builtin_amdgcn_s_barrier();

    for (int t = 0; t < nt; ++t) {
        const int cur = t & 1;
        if (t + 1 < nt) stage(cur ^ 1, t + 1);   // issue first, consume later

        // fragment reads + MFMA -- unpinned, compiler interleaves
        bf16x8 a[2][8], b[2][4];
        #pragma unroll
        for (int kk = 0; kk < 2; ++kk) {
            #pragma unroll
            for (int mi = 0; mi < 8; ++mi) {
                const int lr = wr * 128 + mi * 16 + l15;
                a[kk][mi] = *reinterpret_cast<const bf16x8*>(
                    &As[cur][lr * 64 + (((kk * 4 + l4) ^ (lr & 7)) * 8)]);
            }
            #pragma unroll
            for (int nj = 0; nj < 4; ++nj) {
                const int lr = wc * 64 + nj * 16 + l15;
                b[kk][nj] = *reinterpret_cast<const bf16x8*>(
                    &Bs[cur][lr * 64 + (((kk * 4 + l4) ^ (lr & 7)) * 8)]);
            }
        }
        #pragma unroll
        for (int kk = 0; kk < 2; ++kk)
            #pragma unroll
            for (int mi = 0; mi < 8; ++mi)
                #pragma unroll
                for (int nj = 0; nj < 4; ++nj)
                    acc[mi][nj] = __builtin_amdgcn_mfma_f32_16x16x32_bf16(
                        a[kk][mi], b[kk][nj], acc[mi][nj], 0, 0, 0);

        WAIT_VMCNT_0();                // loads issued a full tile ago
        __builtin_amdgcn_s_barrier();  // single barrier per tile
    }

    // ---- epilogue: bias (+RoPE) + store ----
    float bv[4];
    #pragma unroll
    for (int nf = 0; nf < 4; ++nf)
        bv[nf] = bias[col0 + wc * 64 + nf * 16 + l15];

    const bool doRope = ROPE && (col0 < 2 * C_);   // block-uniform (256 | 2048)

    #pragma unroll
    for (int mf = 0; mf < 8; ++mf) {
        #pragma unroll
        for (int rr = 0; rr < 4; ++rr) {
            const int row = row0 + wr * 128 + mf * 16 + l4 * 4 + rr;
            const int t   = row & (T_ - 1);
            #pragma unroll
            for (int nf = 0; nf < 4; ++nf) {
                const int col = col0 + wc * 64 + nf * 16 + l15;
                float v = acc[mf][nf][rr] + bv[nf];
                if (doRope) {
                    const float partner = __shfl_xor(v, 1);
                    const float2 sc = tab[t * HALF + ((col & 63) >> 1)];
                    v = v * sc.y + ((col & 1) ? partner : -partner) * sc.x;
                }
                if (BF16OUT)
                    ((unsigned short*)Cout)[(size_t)row * N + col] = f2bf(v);
                else
                    ((float*)Cout)[(size_t)row * N + col] = v;
            }
        }
    }
}

// ---------------------------------------------------------------------------
// Flash attention, 32x32 MFMA, swapped operands, PAIRED causal q-tiles,
// double-buffered K/V with counted vmcnt(8) prefetch. (unchanged)
// ---------------------------------------------------------------------------
__global__ __launch_bounds__(256, 2) void attn_mfma4_kernel(
    const unsigned short* __restrict__ qkv,   // roped qkv, bf16
    const unsigned short* __restrict__ vt,    // V^T global [(b*H+h)*64+d][T]
    unsigned short* __restrict__ out)         // [B*T][C] bf16
{
    __shared__ unsigned short Ks[2][128 * 64];   // [j][d], swizzled
    __shared__ unsigned short Vs[2][64 * 128];   // [d][j], swizzled

    const int idx = blockIdx.x;
    const int bh  = idx & 63;                 // b*16 + h
    const int qp  = idx >> 6;                 // 0..7
    const int b   = bh >> 4;
    const int h   = bh & 15;
    const int qtA = qp;
    const int qtB = 15 - qp;

    const int tid  = threadIdx.x;
    const int lane = tid & 63;
    const int w    = tid >> 6;
    const int l31  = lane & 31;
    const int hi   = lane >> 5;

    const int qwA = qtA * 128 + w * 32;
    const int qgA = qwA + l31;
    const int qwB = qtB * 128 + w * 32;
    const int qgB = qwB + l31;

    // Q fragments
    bf16x8 aqA[4], aqB[4];
    {
        const unsigned short* qpA = &qkv[(size_t)(b * T_ + qgA) * QKV_N + h * HS + hi * 8];
        const unsigned short* qpB = &qkv[(size_t)(b * T_ + qgB) * QKV_N + h * HS + hi * 8];
        #pragma unroll
        for (int kc = 0; kc < 4; ++kc) {
            aqA[kc] = *reinterpret_cast<const bf16x8*>(qpA + kc * 16);
            aqB[kc] = *reinterpret_cast<const bf16x8*>(qpB + kc * 16);
        }
    }

    f32x16 accA0 = {}, accA1 = {}, accB0 = {}, accB1 = {};
    float mA = -INFINITY, lA = 0.f, mB = -INFINITY, lB = 0.f;

    const float SCALE = 0.18033688011112042f;  // 0.125 * log2(e)

    auto stageKV = [&](int buf, int it) {
        #pragma unroll
        for (int n = 0; n < 4; ++n) {
            const int r  = n * 32 + (tid >> 3);
            const int sk = ((tid & 7) ^ (r & 7)) * 8;
            gload16(&qkv[(size_t)(b * T_ + it * 128 + r) * QKV_N + C_ + h * HS + sk],
                    &Ks[buf][(n * 256 + tid) * 8]);
        }
        #pragma unroll
        for (int n = 0; n < 4; ++n) {
            const int d  = n * 16 + (tid >> 4);
            const int sv = ((tid & 15) ^ (d & 7)) * 8;
            gload16(&vt[((size_t)(bh * HS + d)) * T_ + it * 128 + sv],
                    &Vs[buf][(n * 256 + tid) * 8]);
        }
    };

    auto process = [&](const unsigned short* Kb, const unsigned short* Vb,
                       const bf16x8* aq, f32x16& a0, f32x16& a1,
                       float& mval, float& lval, int qw, int qg,
                       int sub, int kbase) {
        // ---- S^T = K @ Q^T (two 32-j tiles within this 64 half) ----
        f32x16 st0 = {}, st1 = {};
        #pragma unroll
        for (int kc = 0; kc < 4; ++kc) {
            const int bo = kc * 32 + hi * 16;          // byte offset in 128B K row
            const int r0 = sub * 64 + l31;
            const bf16x8 ak0 = *reinterpret_cast<const bf16x8*>(
                &Kb[r0 * 64 + ((bo ^ ((r0 & 7) << 4)) >> 1)]);
            st0 = __builtin_amdgcn_mfma_f32_32x32x16_bf16(ak0, aq[kc], st0, 0, 0, 0);
            const int r1 = r0 + 32;
            const bf16x8 ak1 = *reinterpret_cast<const bf16x8*>(
                &Kb[r1 * 64 + ((bo ^ ((r1 & 7) << 4)) >> 1)]);
            st1 = __builtin_amdgcn_mfma_f32_32x32x16_bf16(ak1, aq[kc], st1, 0, 0, 0);
        }

        // ---- scale + causal mask (exp2 space) ----
        float p[32];
        if (kbase + 63 > qw) {
            #pragma unroll
            for (int r = 0; r < 16; ++r) {
                const int j0 = kbase + (r & 3) + 8 * (r >> 2) + 4 * hi;
                p[r]      = (j0      <= qg) ? st0[r] * SCALE : -INFINITY;
                p[r + 16] = (j0 + 32 <= qg) ? st1[r] * SCALE : -INFINITY;
            }
        } else {
            #pragma unroll
            for (int r = 0; r < 16; ++r) {
                p[r]      = st0[r] * SCALE;
                p[r + 16] = st1[r] * SCALE;
            }
        }

        // ---- online softmax, per-lane (q = lane&31) ----
        float tm = p[0];
        #pragma unroll
        for (int r = 1; r < 32; ++r) tm = fmaxf(tm, p[r]);
        tm = fmaxf(tm, __shfl_xor(tm, 32));

        const bool upd = (tm > mval + 8.f);          // defer-max THR=8 (log2)
        if (__ballot(upd)) {
            const float nm = upd ? tm : mval;
            const float sf = exp2f(mval - nm);
            lval *= sf;
            #pragma unroll
            for (int r = 0; r < 16; ++r) { a0[r] *= sf; a1[r] *= sf; }
            mval = nm;
        }

        float rs = 0.f;
        #pragma unroll
        for (int r = 0; r < 32; ++r) { p[r] = exp2f(p[r] - mval); rs += p[r]; }
        rs += __shfl_xor(rs, 32);
        lval += rs;

        // ---- P fragments + PV: O^T += Vt @ P ----
        #pragma unroll
        for (int jt = 0; jt < 2; ++jt) {
            #pragma unroll
            for (int c = 0; c < 2; ++c) {
                const int base = jt * 16 + c * 8;
                const unsigned pa = cvtpk_bf16(p[base + 0], p[base + 1]);
                const unsigned pb = cvtpk_bf16(p[base + 2], p[base + 3]);
                const unsigned pc = cvtpk_bf16(p[base + 4], p[base + 5]);
                const unsigned pd = cvtpk_bf16(p[base + 6], p[base + 7]);
                const unsigned pas = (unsigned)__shfl_xor((int)pa, 32);
                const unsigned pbs = (unsigned)__shfl_xor((int)pb, 32);
                const unsigned pcs = (unsigned)__shfl_xor((int)pc, 32);
                const unsigned pds = (unsigned)__shfl_xor((int)pd, 32);
                int4 bw;
                bw.x = (int)(hi ? pcs : pa);
                bw.y = (int)(hi ? pds : pb);
                bw.z = (int)(hi ? pc  : pas);
                bw.w = (int)(hi ? pd  : pbs);
                const bf16x8 bfrag = __builtin_bit_cast(bf16x8, bw);

                const int lslot = sub * 8 + (jt * 2 + c) * 2 + hi;  // 16B slot in 256B Vs row
                const int d0 = l31;
                const bf16x8 av0 = *reinterpret_cast<const bf16x8*>(
                    &Vb[d0 * 128 + (lslot ^ (d0 & 7)) * 8]);
                a0 = __builtin_amdgcn_mfma_f32_32x32x16_bf16(av0, bfrag, a0, 0, 0, 0);
                const int d1 = 32 + l31;
                const bf16x8 av1 = *reinterpret_cast<const bf16x8*>(
                    &Vb[d1 * 128 + (lslot ^ (d1 & 7)) * 8]);
                a1 = __builtin_amdgcn_mfma_f32_32x32x16_bf16(av1, bfrag, a1, 0, 0, 0);
            }
        }
    };

    const int nIter = qtB + 1;                       // 128-wide k chunks
    stageKV(0, 0);
    for (int it = 0; it < nIter; ++it) {
        const int cur = it & 1;
        __builtin_amdgcn_sched_barrier(0);
        if (it + 1 < nIter) {
            stageKV(cur ^ 1, it + 1);
            WAIT_VMCNT_8();
        } else {
            WAIT_VMCNT_0();
        }
        __builtin_amdgcn_s_barrier();
        __builtin_amdgcn_sched_barrier(0);

        const unsigned short* Kb = &Ks[cur][0];
        const unsigned short* Vb = &Vs[cur][0];
        #pragma unroll
        for (int sub = 0; sub < 2; ++sub) {
            const int kbase = it * 128 + sub * 64;
            if (kbase <= qwA + 31)
                process(Kb, Vb, aqA, accA0, accA1, mA, lA, qwA, qgA, sub, kbase);
            if (kbase <= qwB + 31)
                process(Kb, Vb, aqB, accB0, accB1, mB, lB, qwB, qgB, sub, kbase);
        }
        __builtin_amdgcn_sched_barrier(0);
        __builtin_amdgcn_s_barrier();
    }

    // ---- write O = acc^T / l ----
    {
        const float inv = 1.0f / lA;
        unsigned short* orow = &out[(size_t)(b * T_ + qgA) * C_ + h * HS];
        #pragma unroll
        for (int g = 0; g < 4; ++g) {
            uint2 wv;
            wv.x = cvtpk_bf16(accA0[4 * g + 0] * inv, accA0[4 * g + 1] * inv);
            wv.y = cvtpk_bf16(accA0[4 * g + 2] * inv, accA0[4 * g + 3] * inv);
            *reinterpret_cast<uint2*>(&orow[8 * g + 4 * hi]) = wv;
            uint2 wv1;
            wv1.x = cvtpk_bf16(accA1[4 * g + 0] * inv, accA1[4 * g + 1] * inv);
            wv1.y = cvtpk_bf16(accA1[4 * g + 2] * inv, accA1[4 * g + 3] * inv);
            *reinterpret_cast<uint2*>(&orow[32 + 8 * g + 4 * hi]) = wv1;
        }
    }
    {
        const float inv = 1.0f / lB;
        unsigned short* orow = &out[(size_t)(b * T_ + qgB) * C_ + h * HS];
        #pragma unroll
        for (int g = 0; g < 4; ++g) {
            uint2 wv;
            wv.x = cvtpk_bf16(accB0[4 * g + 0] * inv, accB0[4 * g + 1] * inv);
            wv.y = cvtpk_bf16(accB0[4 * g + 2] * inv, accB0[4 * g + 3] * inv);
            *reinterpret_cast<uint2*>(&orow[8 * g + 4 * hi]) = wv;
            uint2 wv1;
            wv1.x = cvtpk_bf16(accB1[4 * g + 0] * inv, accB1[4 * g + 1] * inv);
            wv1.y = cvtpk_bf16(accB1[4 * g + 2] * inv, accB1[4 * g + 3] * inv);
            *reinterpret_cast<uint2*>(&orow[32 + 8 * g + 4 * hi]) = wv1;
        }
    }
}

// ---------------------------------------------------------------------------
extern "C" void kernel_launch(void* const* d_in, const int* in_sizes, int n_in,
                              void* d_out, int out_size, void* d_ws, size_t ws_size,
                              hipStream_t stream)
{
    const float* x    = (const float*)d_in[0];   // [B,T,C]
    const float* Wqkv = (const float*)d_in[1];   // [C,3C]
    const float* bqkv = (const float*)d_in[2];   // [3C]
    const float* Wout = (const float*)d_in[3];   // [C,C]
    const float* bout = (const float*)d_in[4];   // [C]
    float* out = (float*)d_out;                  // [B,T,C] fp32

    char* ws = (char*)d_ws;
    unsigned short* qkvb  = (unsigned short*)ws;                       // 50,331,648
    unsigned short* xb    = (unsigned short*)(ws + 50331648);          // 16,777,216
    unsigned short* attnb = (unsigned short*)(ws + 67108864);          // 16,777,216
    unsigned short* vt_g  = (unsigned short*)(ws + 83886080);          // 16,777,216
    unsigned short* Wqkvt = (unsigned short*)(ws + 100663296);         //  6,291,456
    unsigned short* Woutt = (unsigned short*)(ws + 106954752);         //  2,097,152
    float2* tab           = (float2*)(ws + 109051904);                 //    524,288

    // 1) casts / transposes / tables
    cast_bf16_kernel<<<(size_t)M_ * C_ / (8 * 256), 256, 0, stream>>>(x, xb);
    transpose_cast_kernel<<<dim3(QKV_N / 32, C_ / 32), 256, 0, stream>>>(Wqkv, Wqkvt, C_, QKV_N);
    transpose_cast_kernel<<<dim3(C_ / 32, C_ / 32), 256, 0, stream>>>(Wout, Woutt, C_, C_);
    rope_table_kernel<<<(T_ * HALF) / 256, 256, 0, stream>>>(tab);

    // 2) QKV projection with fused RoPE on q,k columns (bf16 out)
    //    grid = (8192/256) * (3072/256) = 32*12 = 384 blocks
    gemm_v7_kernel<true, true><<<(M_ / 256) * (QKV_N / 256), 512, 0, stream>>>(
        xb, Wqkvt, bqkv, tab, qkvb, M_, QKV_N, C_, QKV_N / 256);

    // 3) V^T precompute
    vtrans_kernel<<<B_ * H_ * (T_ / 64), 256, 0, stream>>>(qkvb, vt_g);

    // 4) attention -> attnb [B,T,C] bf16 (paired causal q-tiles, pipelined)
    attn_mfma4_kernel<<<B_ * H_ * (T_ / 256), 256, 0, stream>>>(qkvb, vt_g, attnb);

    // 5) output projection (fp32 out): grid = 32*4 = 128 blocks
    gemm_v7_kernel<false, false><<<(M_ / 256) * (C_ / 256), 512, 0, stream>>>(
        attnb, Woutt, bout, nullptr, out, M_, C_, C_, C_ / 256);
}

// Round 9
// 222.299 us; speedup vs baseline: 1.1077x; 1.1077x over previous
//
#include <hip/hip_runtime.h>
#include <math.h>

// Problem constants (B=4, T=2048, C=1024, H=16, hs=64)
#define B_   4
#define T_   2048
#define C_   1024
#define H_   16
#define HS   64
#define HALF 32
#define QKV_N (3 * C_)      // 3072
#define M_    (B_ * T_)     // 8192

using bf16x8 = __attribute__((ext_vector_type(8))) short;
using f32x4  = __attribute__((ext_vector_type(4))) float;
using f32x16 = __attribute__((ext_vector_type(16))) float;

__device__ __forceinline__ unsigned short f2bf(float f) {
    unsigned u = __builtin_bit_cast(unsigned, f);
    u = (u + 0x7FFFu + ((u >> 16) & 1u)) >> 16;
    return (unsigned short)u;
}
__device__ __forceinline__ float bf2f(unsigned short b) {
    return __builtin_bit_cast(float, (unsigned)b << 16);
}
__device__ __forceinline__ unsigned cvtpk_bf16(float lo, float hi_) {
    unsigned r;
    asm("v_cvt_pk_bf16_f32 %0, %1, %2" : "=v"(r) : "v"(lo), "v"(hi_));
    return r;
}
__device__ __forceinline__ void gload16(const void* g, void* l) {
    __builtin_amdgcn_global_load_lds(
        (const __attribute__((address_space(1))) unsigned int*)g,
        (__attribute__((address_space(3))) unsigned int*)l, 16, 0, 0);
}
#define WAIT_VMCNT_8() asm volatile("s_waitcnt vmcnt(8)" ::: "memory")
#define WAIT_VMCNT_0() asm volatile("s_waitcnt vmcnt(0)" ::: "memory")

// ---------------------------------------------------------------------------
// prep: blocks [0,4096): fp32->bf16 cast of x (8 elems/thread);
//       blocks [4096,4352): RoPE sin/cos table.
// ---------------------------------------------------------------------------
__global__ __launch_bounds__(256) void prep_kernel(
    const float* __restrict__ in, unsigned short* __restrict__ out,
    float2* __restrict__ tab)
{
    const int bid = blockIdx.x;
    if (bid < 4096) {
        const size_t i = ((size_t)bid * 256 + threadIdx.x) * 8;
        const float4 a = *reinterpret_cast<const float4*>(&in[i]);
        const float4 b = *reinterpret_cast<const float4*>(&in[i + 4]);
        bf16x8 v;
        v[0] = f2bf(a.x); v[1] = f2bf(a.y); v[2] = f2bf(a.z); v[3] = f2bf(a.w);
        v[4] = f2bf(b.x); v[5] = f2bf(b.y); v[6] = f2bf(b.z); v[7] = f2bf(b.w);
        *reinterpret_cast<bf16x8*>(&out[i]) = v;
    } else {
        const int idx = (bid - 4096) * 256 + threadIdx.x;   // 0 .. T_*HALF-1
        const int t = idx / HALF;
        const int i = idx % HALF;
        const float theta = powf(10000.0f, -(float)i / (float)HALF);
        const float ang = (float)t * theta;
        float sn, cs;
        sincosf(ang, &sn, &cs);
        tab[idx] = make_float2(sn, cs);
    }
}

// ---------------------------------------------------------------------------
// wtrans: both weight transposes in one dispatch.
// blocks [0,3072): Wqkv [1024][3072] -> Wqkvt [3072][1024]
// blocks [3072,4096): Wout [1024][1024] -> Woutt [1024][1024]
// ---------------------------------------------------------------------------
__global__ __launch_bounds__(256) void wtrans_kernel(
    const float* __restrict__ Wqkv, const float* __restrict__ Wout,
    unsigned short* __restrict__ Wqkvt, unsigned short* __restrict__ Woutt)
{
    __shared__ float tile[32][33];
    const int bid = blockIdx.x;
    const float* W;
    unsigned short* Wt;
    int N, k0, n0;
    if (bid < 3072) {
        W = Wqkv; Wt = Wqkvt; N = QKV_N;
        n0 = (bid % 96) * 32; k0 = (bid / 96) * 32;
    } else {
        const int r2 = bid - 3072;
        W = Wout; Wt = Woutt; N = C_;
        n0 = (r2 % 32) * 32; k0 = (r2 / 32) * 32;
    }
    const int K = C_;
    const int r = threadIdx.x / 32;
    const int c = threadIdx.x % 32;
    #pragma unroll
    for (int it = 0; it < 4; ++it)
        tile[r + it * 8][c] = W[(size_t)(k0 + r + it * 8) * N + n0 + c];
    __syncthreads();
    #pragma unroll
    for (int it = 0; it < 4; ++it)
        Wt[(size_t)(n0 + r + it * 8) * K + k0 + c] = f2bf(tile[c][r + it * 8]);
}

// ---------------------------------------------------------------------------
// V^T precompute: qkv v-slice [b*T+t][2C + h*64 + d] -> vt[((b*H+h)*64+d)*T + t]
// ---------------------------------------------------------------------------
__global__ __launch_bounds__(256) void vtrans_kernel(
    const unsigned short* __restrict__ qkv, unsigned short* __restrict__ vt)
{
    __shared__ unsigned short tile[64][72];
    const int tt = blockIdx.x & 31;
    const int h  = (blockIdx.x >> 5) & 15;
    const int b  = blockIdx.x >> 9;
    const int tid = threadIdx.x;
    const int r  = tid >> 2;          // 0..63
    const int c0 = (tid & 3) * 16;    // 0,16,32,48
    {
        const unsigned short* g =
            &qkv[(size_t)(b * T_ + tt * 64 + r) * QKV_N + 2 * C_ + h * HS + c0];
        const bf16x8 v0 = *reinterpret_cast<const bf16x8*>(g);
        const bf16x8 v1 = *reinterpret_cast<const bf16x8*>(g + 8);
        *reinterpret_cast<bf16x8*>(&tile[r][c0])     = v0;
        *reinterpret_cast<bf16x8*>(&tile[r][c0 + 8]) = v1;
    }
    __syncthreads();
    bf16x8 o0, o1;
    #pragma unroll
    for (int u = 0; u < 8; ++u) o0[u] = tile[c0 + u][r];
    #pragma unroll
    for (int u = 0; u < 8; ++u) o1[u] = tile[c0 + 8 + u][r];
    unsigned short* g = &vt[((size_t)((b * H_ + h) * HS + r)) * T_ + tt * 64 + c0];
    *reinterpret_cast<bf16x8*>(g)     = o0;
    *reinterpret_cast<bf16x8*>(g + 8) = o1;
}

// ---------------------------------------------------------------------------
// bf16 MFMA GEMM (m97 structure, R3 body): C = A @ Bt^T + bias (+RoPE).
// 128x128 tile, BK=32, 256 threads = 4 waves (2x2). 2-barrier loop,
// global_load_lds width-16 staging, linear LDS.
// NEW vs R3: 1D grid with 4x2 XCD-region swizzle — each XCD owns a
// contiguous (nby/4) x (nbx/2) panel region, row-major within, so A-panels
// stay hot in that XCD's L2 (predicted FETCH 77 -> ~55 MB).
// ---------------------------------------------------------------------------
template <bool BF16OUT, bool ROPE>
__global__ __launch_bounds__(256) void gemm_mfma_kernel(
    const unsigned short* __restrict__ A, const unsigned short* __restrict__ Bt,
    const float* __restrict__ bias, const float2* __restrict__ tab,
    void* __restrict__ Cout, int M, int N, int K, int nbx, int nby)
{
    __shared__ unsigned short As[128 * 32];
    __shared__ unsigned short Bs[128 * 32];

    const int tid  = threadIdx.x;
    const int lane = tid & 63;
    const int wave = tid >> 6;
    const int wr   = wave >> 1;
    const int wc   = wave & 1;
    const int l15  = lane & 15;
    const int l4   = lane >> 4;

    // ---- 4x2 XCD-region block swizzle ----
    const int bid  = blockIdx.x;
    const int xcd  = bid & 7;             // dispatch round-robins XCDs
    const int w    = bid >> 3;            // index within this XCD's region
    const int cpr  = nbx >> 1;            // cols per region
    const int rpr  = nby >> 2;            // rows per region
    const int by   = ((xcd >> 1) * rpr) + (w / cpr);
    const int bx   = ((xcd & 1) * cpr) + (w % cpr);
    const int row0 = by * 128;
    const int col0 = bx * 128;

    f32x4 acc[4][4] = {};
    const int ar = tid >> 2, ac = (tid & 3) * 8;

    for (int k0 = 0; k0 < K; k0 += 32) {
        gload16(&A[(size_t)(row0 + ar) * K + k0 + ac],       &As[tid * 8]);
        gload16(&A[(size_t)(row0 + 64 + ar) * K + k0 + ac],  &As[(tid + 256) * 8]);
        gload16(&Bt[(size_t)(col0 + ar) * K + k0 + ac],      &Bs[tid * 8]);
        gload16(&Bt[(size_t)(col0 + 64 + ar) * K + k0 + ac], &Bs[(tid + 256) * 8]);
        __syncthreads();

        bf16x8 a[4], b[4];
        #pragma unroll
        for (int mi = 0; mi < 4; ++mi)
            a[mi] = *reinterpret_cast<const bf16x8*>(
                &As[(wr * 64 + mi * 16 + l15) * 32 + l4 * 8]);
        #pragma unroll
        for (int nj = 0; nj < 4; ++nj)
            b[nj] = *reinterpret_cast<const bf16x8*>(
                &Bs[(wc * 64 + nj * 16 + l15) * 32 + l4 * 8]);
        #pragma unroll
        for (int mi = 0; mi < 4; ++mi)
            #pragma unroll
            for (int nj = 0; nj < 4; ++nj)
                acc[mi][nj] = __builtin_amdgcn_mfma_f32_16x16x32_bf16(
                    a[mi], b[nj], acc[mi][nj], 0, 0, 0);
        __syncthreads();
    }

    float bv[4];
    #pragma unroll
    for (int nj = 0; nj < 4; ++nj)
        bv[nj] = bias[col0 + wc * 64 + nj * 16 + l15];

    const bool doRope = ROPE && (col0 < 2 * C_);   // block-uniform

    #pragma unroll
    for (int mi = 0; mi < 4; ++mi) {
        #pragma unroll
        for (int r = 0; r < 4; ++r) {
            const int row = row0 + wr * 64 + mi * 16 + l4 * 4 + r;
            const int t   = row & (T_ - 1);
            #pragma unroll
            for (int nj = 0; nj < 4; ++nj) {
                const int col = col0 + wc * 64 + nj * 16 + l15;
                float v = acc[mi][nj][r] + bv[nj];
                if (doRope) {
                    const float partner = __shfl_xor(v, 1);
                    const float2 sc = tab[t * HALF + ((col & 63) >> 1)];
                    v = v * sc.y + ((col & 1) ? partner : -partner) * sc.x;
                }
                if (BF16OUT)
                    ((unsigned short*)Cout)[(size_t)row * N + col] = f2bf(v);
                else
                    ((float*)Cout)[(size_t)row * N + col] = v;
            }
        }
    }
}

// ---------------------------------------------------------------------------
// Flash attention, 32x32 MFMA, swapped operands, PAIRED causal q-tiles,
// double-buffered K/V with counted vmcnt(8) prefetch. (R4 version, verbatim)
// ---------------------------------------------------------------------------
__global__ __launch_bounds__(256, 2) void attn_mfma4_kernel(
    const unsigned short* __restrict__ qkv,   // roped qkv, bf16
    const unsigned short* __restrict__ vt,    // V^T global [(b*H+h)*64+d][T]
    unsigned short* __restrict__ out)         // [B*T][C] bf16
{
    __shared__ unsigned short Ks[2][128 * 64];   // [j][d], swizzled
    __shared__ unsigned short Vs[2][64 * 128];   // [d][j], swizzled

    const int idx = blockIdx.x;
    const int bh  = idx & 63;                 // b*16 + h
    const int qp  = idx >> 6;                 // 0..7
    const int b   = bh >> 4;
    const int h   = bh & 15;
    const int qtA = qp;
    const int qtB = 15 - qp;

    const int tid  = threadIdx.x;
    const int lane = tid & 63;
    const int w    = tid >> 6;
    const int l31  = lane & 31;
    const int hi   = lane >> 5;

    const int qwA = qtA * 128 + w * 32;
    const int qgA = qwA + l31;
    const int qwB = qtB * 128 + w * 32;
    const int qgB = qwB + l31;

    // Q fragments
    bf16x8 aqA[4], aqB[4];
    {
        const unsigned short* qpA = &qkv[(size_t)(b * T_ + qgA) * QKV_N + h * HS + hi * 8];
        const unsigned short* qpB = &qkv[(size_t)(b * T_ + qgB) * QKV_N + h * HS + hi * 8];
        #pragma unroll
        for (int kc = 0; kc < 4; ++kc) {
            aqA[kc] = *reinterpret_cast<const bf16x8*>(qpA + kc * 16);
            aqB[kc] = *reinterpret_cast<const bf16x8*>(qpB + kc * 16);
        }
    }

    f32x16 accA0 = {}, accA1 = {}, accB0 = {}, accB1 = {};
    float mA = -INFINITY, lA = 0.f, mB = -INFINITY, lB = 0.f;

    const float SCALE = 0.18033688011112042f;  // 0.125 * log2(e)

    auto stageKV = [&](int buf, int it) {
        #pragma unroll
        for (int n = 0; n < 4; ++n) {
            const int r  = n * 32 + (tid >> 3);
            const int sk = ((tid & 7) ^ (r & 7)) * 8;
            gload16(&qkv[(size_t)(b * T_ + it * 128 + r) * QKV_N + C_ + h * HS + sk],
                    &Ks[buf][(n * 256 + tid) * 8]);
        }
        #pragma unroll
        for (int n = 0; n < 4; ++n) {
            const int d  = n * 16 + (tid >> 4);
            const int sv = ((tid & 15) ^ (d & 7)) * 8;
            gload16(&vt[((size_t)(bh * HS + d)) * T_ + it * 128 + sv],
                    &Vs[buf][(n * 256 + tid) * 8]);
        }
    };

    auto process = [&](const unsigned short* Kb, const unsigned short* Vb,
                       const bf16x8* aq, f32x16& a0, f32x16& a1,
                       float& mval, float& lval, int qw, int qg,
                       int sub, int kbase) {
        // ---- S^T = K @ Q^T (two 32-j tiles within this 64 half) ----
        f32x16 st0 = {}, st1 = {};
        #pragma unroll
        for (int kc = 0; kc < 4; ++kc) {
            const int bo = kc * 32 + hi * 16;          // byte offset in 128B K row
            const int r0 = sub * 64 + l31;
            const bf16x8 ak0 = *reinterpret_cast<const bf16x8*>(
                &Kb[r0 * 64 + ((bo ^ ((r0 & 7) << 4)) >> 1)]);
            st0 = __builtin_amdgcn_mfma_f32_32x32x16_bf16(ak0, aq[kc], st0, 0, 0, 0);
            const int r1 = r0 + 32;
            const bf16x8 ak1 = *reinterpret_cast<const bf16x8*>(
                &Kb[r1 * 64 + ((bo ^ ((r1 & 7) << 4)) >> 1)]);
            st1 = __builtin_amdgcn_mfma_f32_32x32x16_bf16(ak1, aq[kc], st1, 0, 0, 0);
        }

        // ---- scale + causal mask (exp2 space) ----
        float p[32];
        if (kbase + 63 > qw) {
            #pragma unroll
            for (int r = 0; r < 16; ++r) {
                const int j0 = kbase + (r & 3) + 8 * (r >> 2) + 4 * hi;
                p[r]      = (j0      <= qg) ? st0[r] * SCALE : -INFINITY;
                p[r + 16] = (j0 + 32 <= qg) ? st1[r] * SCALE : -INFINITY;
            }
        } else {
            #pragma unroll
            for (int r = 0; r < 16; ++r) {
                p[r]      = st0[r] * SCALE;
                p[r + 16] = st1[r] * SCALE;
            }
        }

        // ---- online softmax, per-lane (q = lane&31) ----
        float tm = p[0];
        #pragma unroll
        for (int r = 1; r < 32; ++r) tm = fmaxf(tm, p[r]);
        tm = fmaxf(tm, __shfl_xor(tm, 32));

        const bool upd = (tm > mval + 8.f);          // defer-max THR=8 (log2)
        if (__ballot(upd)) {
            const float nm = upd ? tm : mval;
            const float sf = exp2f(mval - nm);
            lval *= sf;
            #pragma unroll
            for (int r = 0; r < 16; ++r) { a0[r] *= sf; a1[r] *= sf; }
            mval = nm;
        }

        float rs = 0.f;
        #pragma unroll
        for (int r = 0; r < 32; ++r) { p[r] = exp2f(p[r] - mval); rs += p[r]; }
        rs += __shfl_xor(rs, 32);
        lval += rs;

        // ---- P fragments + PV: O^T += Vt @ P ----
        #pragma unroll
        for (int jt = 0; jt < 2; ++jt) {
            #pragma unroll
            for (int c = 0; c < 2; ++c) {
                const int base = jt * 16 + c * 8;
                const unsigned pa = cvtpk_bf16(p[base + 0], p[base + 1]);
                const unsigned pb = cvtpk_bf16(p[base + 2], p[base + 3]);
                const unsigned pc = cvtpk_bf16(p[base + 4], p[base + 5]);
                const unsigned pd = cvtpk_bf16(p[base + 6], p[base + 7]);
                const unsigned pas = (unsigned)__shfl_xor((int)pa, 32);
                const unsigned pbs = (unsigned)__shfl_xor((int)pb, 32);
                const unsigned pcs = (unsigned)__shfl_xor((int)pc, 32);
                const unsigned pds = (unsigned)__shfl_xor((int)pd, 32);
                int4 bw;
                bw.x = (int)(hi ? pcs : pa);
                bw.y = (int)(hi ? pds : pb);
                bw.z = (int)(hi ? pc  : pas);
                bw.w = (int)(hi ? pd  : pbs);
                const bf16x8 bfrag = __builtin_bit_cast(bf16x8, bw);

                const int lslot = sub * 8 + (jt * 2 + c) * 2 + hi;  // 16B slot in 256B Vs row
                const int d0 = l31;
                const bf16x8 av0 = *reinterpret_cast<const bf16x8*>(
                    &Vb[d0 * 128 + (lslot ^ (d0 & 7)) * 8]);
                a0 = __builtin_amdgcn_mfma_f32_32x32x16_bf16(av0, bfrag, a0, 0, 0, 0);
                const int d1 = 32 + l31;
                const bf16x8 av1 = *reinterpret_cast<const bf16x8*>(
                    &Vb[d1 * 128 + (lslot ^ (d1 & 7)) * 8]);
                a1 = __builtin_amdgcn_mfma_f32_32x32x16_bf16(av1, bfrag, a1, 0, 0, 0);
            }
        }
    };

    const int nIter = qtB + 1;                       // 128-wide k chunks
    stageKV(0, 0);
    for (int it = 0; it < nIter; ++it) {
        const int cur = it & 1;
        __builtin_amdgcn_sched_barrier(0);
        if (it + 1 < nIter) {
            stageKV(cur ^ 1, it + 1);
            WAIT_VMCNT_8();
        } else {
            WAIT_VMCNT_0();
        }
        __builtin_amdgcn_s_barrier();
        __builtin_amdgcn_sched_barrier(0);

        const unsigned short* Kb = &Ks[cur][0];
        const unsigned short* Vb = &Vs[cur][0];
        #pragma unroll
        for (int sub = 0; sub < 2; ++sub) {
            const int kbase = it * 128 + sub * 64;
            if (kbase <= qwA + 31)
                process(Kb, Vb, aqA, accA0, accA1, mA, lA, qwA, qgA, sub, kbase);
            if (kbase <= qwB + 31)
                process(Kb, Vb, aqB, accB0, accB1, mB, lB, qwB, qgB, sub, kbase);
        }
        __builtin_amdgcn_sched_barrier(0);
        __builtin_amdgcn_s_barrier();
    }

    // ---- write O = acc^T / l ----
    {
        const float inv = 1.0f / lA;
        unsigned short* orow = &out[(size_t)(b * T_ + qgA) * C_ + h * HS];
        #pragma unroll
        for (int g = 0; g < 4; ++g) {
            uint2 wv;
            wv.x = cvtpk_bf16(accA0[4 * g + 0] * inv, accA0[4 * g + 1] * inv);
            wv.y = cvtpk_bf16(accA0[4 * g + 2] * inv, accA0[4 * g + 3] * inv);
            *reinterpret_cast<uint2*>(&orow[8 * g + 4 * hi]) = wv;
            uint2 wv1;
            wv1.x = cvtpk_bf16(accA1[4 * g + 0] * inv, accA1[4 * g + 1] * inv);
            wv1.y = cvtpk_bf16(accA1[4 * g + 2] * inv, accA1[4 * g + 3] * inv);
            *reinterpret_cast<uint2*>(&orow[32 + 8 * g + 4 * hi]) = wv1;
        }
    }
    {
        const float inv = 1.0f / lB;
        unsigned short* orow = &out[(size_t)(b * T_ + qgB) * C_ + h * HS];
        #pragma unroll
        for (int g = 0; g < 4; ++g) {
            uint2 wv;
            wv.x = cvtpk_bf16(accB0[4 * g + 0] * inv, accB0[4 * g + 1] * inv);
            wv.y = cvtpk_bf16(accB0[4 * g + 2] * inv, accB0[4 * g + 3] * inv);
            *reinterpret_cast<uint2*>(&orow[8 * g + 4 * hi]) = wv;
            uint2 wv1;
            wv1.x = cvtpk_bf16(accB1[4 * g + 0] * inv, accB1[4 * g + 1] * inv);
            wv1.y = cvtpk_bf16(accB1[4 * g + 2] * inv, accB1[4 * g + 3] * inv);
            *reinterpret_cast<uint2*>(&orow[32 + 8 * g + 4 * hi]) = wv1;
        }
    }
}

// ---------------------------------------------------------------------------
extern "C" void kernel_launch(void* const* d_in, const int* in_sizes, int n_in,
                              void* d_out, int out_size, void* d_ws, size_t ws_size,
                              hipStream_t stream)
{
    const float* x    = (const float*)d_in[0];   // [B,T,C]
    const float* Wqkv = (const float*)d_in[1];   // [C,3C]
    const float* bqkv = (const float*)d_in[2];   // [3C]
    const float* Wout = (const float*)d_in[3];   // [C,C]
    const float* bout = (const float*)d_in[4];   // [C]
    float* out = (float*)d_out;                  // [B,T,C] fp32

    char* ws = (char*)d_ws;
    unsigned short* qkvb  = (unsigned short*)ws;                       // 50,331,648
    unsigned short* xb    = (unsigned short*)(ws + 50331648);          // 16,777,216
    unsigned short* attnb = (unsigned short*)(ws + 67108864);          // 16,777,216
    unsigned short* vt_g  = (unsigned short*)(ws + 83886080);          // 16,777,216
    unsigned short* Wqkvt = (unsigned short*)(ws + 100663296);         //  6,291,456
    unsigned short* Woutt = (unsigned short*)(ws + 106954752);         //  2,097,152
    float2* tab           = (float2*)(ws + 109051904);                 //    524,288

    // 1) fused prep (cast + rope table) and fused weight transposes
    prep_kernel<<<4352, 256, 0, stream>>>(x, xb, tab);
    wtrans_kernel<<<4096, 256, 0, stream>>>(Wqkv, Wout, Wqkvt, Woutt);

    // 2) QKV projection with fused RoPE (bf16 out)
    //    grid = 64 row-panels x 24 col-panels = 1536 blocks, XCD-region map
    gemm_mfma_kernel<true, true><<<(M_ / 128) * (QKV_N / 128), 256, 0, stream>>>(
        xb, Wqkvt, bqkv, tab, qkvb, M_, QKV_N, C_, QKV_N / 128, M_ / 128);

    // 3) V^T precompute
    vtrans_kernel<<<B_ * H_ * (T_ / 64), 256, 0, stream>>>(qkvb, vt_g);

    // 4) attention -> attnb [B,T,C] bf16 (paired causal q-tiles, pipelined)
    attn_mfma4_kernel<<<B_ * H_ * (T_ / 256), 256, 0, stream>>>(qkvb, vt_g, attnb);

    // 5) output projection (fp32 out): 64 x 8 = 512 blocks, XCD-region map
    gemm_mfma_kernel<false, false><<<(M_ / 128) * (C_ / 128), 256, 0, stream>>>(
        attnb, Woutt, bout, nullptr, out, M_, C_, C_, C_ / 128, M_ / 128);
}

// Round 10
// 189.623 us; speedup vs baseline: 1.2986x; 1.1723x over previous
//
#include <hip/hip_runtime.h>
#include <math.h>

// Problem constants (B=4, T=2048, C=1024, H=16, hs=64)
#define B_   4
#define T_   2048
#define C_   1024
#define H_   16
#define HS   64
#define HALF 32
#define QKV_N (3 * C_)      // 3072
#define M_    (B_ * T_)     // 8192

using bf16x8 = __attribute__((ext_vector_type(8))) short;
using f32x4  = __attribute__((ext_vector_type(4))) float;
using f32x16 = __attribute__((ext_vector_type(16))) float;
using u16x4  = __attribute__((ext_vector_type(4))) unsigned short;

__device__ __forceinline__ unsigned short f2bf(float f) {
    unsigned u = __builtin_bit_cast(unsigned, f);
    u = (u + 0x7FFFu + ((u >> 16) & 1u)) >> 16;
    return (unsigned short)u;
}
__device__ __forceinline__ float bf2f(unsigned short b) {
    return __builtin_bit_cast(float, (unsigned)b << 16);
}
__device__ __forceinline__ unsigned cvtpk_bf16(float lo, float hi_) {
    unsigned r;
    asm("v_cvt_pk_bf16_f32 %0, %1, %2" : "=v"(r) : "v"(lo), "v"(hi_));
    return r;
}
__device__ __forceinline__ void gload16(const void* g, void* l) {
    __builtin_amdgcn_global_load_lds(
        (const __attribute__((address_space(1))) unsigned int*)g,
        (__attribute__((address_space(3))) unsigned int*)l, 16, 0, 0);
}
#define WAIT_VMCNT_8() asm volatile("s_waitcnt vmcnt(8)" ::: "memory")
#define WAIT_VMCNT_0() asm volatile("s_waitcnt vmcnt(0)" ::: "memory")

// ---------------------------------------------------------------------------
// prep: blocks [0,4096): fp32->bf16 cast of x; blocks [4096,4352): RoPE table.
// ---------------------------------------------------------------------------
__global__ __launch_bounds__(256) void prep_kernel(
    const float* __restrict__ in, unsigned short* __restrict__ out,
    float2* __restrict__ tab)
{
    const int bid = blockIdx.x;
    if (bid < 4096) {
        const size_t i = ((size_t)bid * 256 + threadIdx.x) * 8;
        const float4 a = *reinterpret_cast<const float4*>(&in[i]);
        const float4 b = *reinterpret_cast<const float4*>(&in[i + 4]);
        bf16x8 v;
        v[0] = f2bf(a.x); v[1] = f2bf(a.y); v[2] = f2bf(a.z); v[3] = f2bf(a.w);
        v[4] = f2bf(b.x); v[5] = f2bf(b.y); v[6] = f2bf(b.z); v[7] = f2bf(b.w);
        *reinterpret_cast<bf16x8*>(&out[i]) = v;
    } else {
        const int idx = (bid - 4096) * 256 + threadIdx.x;   // 0 .. T_*HALF-1
        const int t = idx / HALF;
        const int i = idx % HALF;
        const float theta = powf(10000.0f, -(float)i / (float)HALF);
        const float ang = (float)t * theta;
        float sn, cs;
        sincosf(ang, &sn, &cs);
        tab[idx] = make_float2(sn, cs);
    }
}

// ---------------------------------------------------------------------------
// wtrans: both weight transposes in one dispatch.
// ---------------------------------------------------------------------------
__global__ __launch_bounds__(256) void wtrans_kernel(
    const float* __restrict__ Wqkv, const float* __restrict__ Wout,
    unsigned short* __restrict__ Wqkvt, unsigned short* __restrict__ Woutt)
{
    __shared__ float tile[32][33];
    const int bid = blockIdx.x;
    const float* W;
    unsigned short* Wt;
    int N, k0, n0;
    if (bid < 3072) {
        W = Wqkv; Wt = Wqkvt; N = QKV_N;
        n0 = (bid % 96) * 32; k0 = (bid / 96) * 32;
    } else {
        const int r2 = bid - 3072;
        W = Wout; Wt = Woutt; N = C_;
        n0 = (r2 % 32) * 32; k0 = (r2 / 32) * 32;
    }
    const int K = C_;
    const int r = threadIdx.x / 32;
    const int c = threadIdx.x % 32;
    #pragma unroll
    for (int it = 0; it < 4; ++it)
        tile[r + it * 8][c] = W[(size_t)(k0 + r + it * 8) * N + n0 + c];
    __syncthreads();
    #pragma unroll
    for (int it = 0; it < 4; ++it)
        Wt[(size_t)(n0 + r + it * 8) * K + k0 + c] = f2bf(tile[c][r + it * 8]);
}

// ---------------------------------------------------------------------------
// bf16 MFMA GEMM (m97 structure; compile-time dims; strength-reduced addrs).
// 128x128 tile, BK=32, 256 threads = 4 waves (2x2), 2-barrier loop,
// global_load_lds width-16 staging, linear LDS, 4x2 XCD-region swizzle.
// VSPLIT: v-column blocks (col0 >= 2048) write transposed into vt (bf16)
// instead of Cout — fuses the old vtrans kernel into the epilogue.
// ---------------------------------------------------------------------------
template <int N, int K, bool BF16OUT, bool ROPE, bool VSPLIT>
__global__ __launch_bounds__(256, 4) void gemm_mfma_kernel(
    const unsigned short* __restrict__ A, const unsigned short* __restrict__ Bt,
    const float* __restrict__ bias, const float2* __restrict__ tab,
    void* __restrict__ Cout, unsigned short* __restrict__ vt, int nbx, int nby)
{
    __shared__ unsigned short As[128 * 32];
    __shared__ unsigned short Bs[128 * 32];

    const int tid  = threadIdx.x;
    const int lane = tid & 63;
    const int wave = tid >> 6;
    const int wr   = wave >> 1;
    const int wc   = wave & 1;
    const int l15  = lane & 15;
    const int l4   = lane >> 4;

    // ---- 4x2 XCD-region block swizzle ----
    const int bid  = blockIdx.x;
    const int xcd  = bid & 7;
    const int w    = bid >> 3;
    const int cpr  = nbx >> 1;
    const int rpr  = nby >> 2;
    const int by   = ((xcd >> 1) * rpr) + (w / cpr);
    const int bx   = ((xcd & 1) * cpr) + (w % cpr);
    const int row0 = by * 128;
    const int col0 = bx * 128;

    f32x4 acc[4][4] = {};

    // strength-reduced staging pointers (K compile-time: 64*K is immediate)
    const int ar = tid >> 2, ac = (tid & 3) * 8;
    const unsigned short* ap = &A[(size_t)(row0 + ar) * K + ac];
    const unsigned short* bp = &Bt[(size_t)(col0 + ar) * K + ac];

    for (int it = 0; it < K / 32; ++it) {
        gload16(ap,          &As[tid * 8]);
        gload16(ap + 64 * K, &As[(tid + 256) * 8]);
        gload16(bp,          &Bs[tid * 8]);
        gload16(bp + 64 * K, &Bs[(tid + 256) * 8]);
        __syncthreads();

        bf16x8 a[4], b[4];
        #pragma unroll
        for (int mi = 0; mi < 4; ++mi)
            a[mi] = *reinterpret_cast<const bf16x8*>(
                &As[(wr * 64 + mi * 16 + l15) * 32 + l4 * 8]);
        #pragma unroll
        for (int nj = 0; nj < 4; ++nj)
            b[nj] = *reinterpret_cast<const bf16x8*>(
                &Bs[(wc * 64 + nj * 16 + l15) * 32 + l4 * 8]);
        #pragma unroll
        for (int mi = 0; mi < 4; ++mi)
            #pragma unroll
            for (int nj = 0; nj < 4; ++nj)
                acc[mi][nj] = __builtin_amdgcn_mfma_f32_16x16x32_bf16(
                    a[mi], b[nj], acc[mi][nj], 0, 0, 0);
        __syncthreads();
        ap += 32;
        bp += 32;
    }

    float bv[4];
    #pragma unroll
    for (int nj = 0; nj < 4; ++nj)
        bv[nj] = bias[col0 + wc * 64 + nj * 16 + l15];

    if (VSPLIT && col0 >= 2 * C_) {
        // ---- v-columns: write transposed straight into vt[(b*16+h)*64+d][t]
        #pragma unroll
        for (int mi = 0; mi < 4; ++mi) {
            const int rowb = row0 + wr * 64 + mi * 16 + l4 * 4;  // 4 consec rows
            const int b  = rowb >> 11;
            const int t0 = rowb & (T_ - 1);
            #pragma unroll
            for (int nj = 0; nj < 4; ++nj) {
                const int cv = col0 - 2 * C_ + wc * 64 + nj * 16 + l15;
                u16x4 pack;
                #pragma unroll
                for (int r = 0; r < 4; ++r)
                    pack[r] = f2bf(acc[mi][nj][r] + bv[nj]);
                *reinterpret_cast<u16x4*>(
                    &vt[((size_t)(b * H_ * HS + cv)) * T_ + t0]) = pack;
            }
        }
        return;
    }

    const bool doRope = ROPE && (col0 < 2 * C_);

    #pragma unroll
    for (int mi = 0; mi < 4; ++mi) {
        #pragma unroll
        for (int r = 0; r < 4; ++r) {
            const int row = row0 + wr * 64 + mi * 16 + l4 * 4 + r;
            const int t   = row & (T_ - 1);
            #pragma unroll
            for (int nj = 0; nj < 4; ++nj) {
                const int col = col0 + wc * 64 + nj * 16 + l15;
                float v = acc[mi][nj][r] + bv[nj];
                if (doRope) {
                    const float partner = __shfl_xor(v, 1);
                    const float2 sc = tab[t * HALF + ((col & 63) >> 1)];
                    v = v * sc.y + ((col & 1) ? partner : -partner) * sc.x;
                }
                if (BF16OUT)
                    ((unsigned short*)Cout)[(size_t)row * N + col] = f2bf(v);
                else
                    ((float*)Cout)[(size_t)row * N + col] = v;
            }
        }
    }
}

// ---------------------------------------------------------------------------
// Flash attention, 32x32 MFMA, swapped operands, PAIRED causal q-tiles,
// double-buffered K/V with counted vmcnt(8) prefetch. (R4 version, verbatim)
// ---------------------------------------------------------------------------
__global__ __launch_bounds__(256, 2) void attn_mfma4_kernel(
    const unsigned short* __restrict__ qkv,   // roped qkv, bf16
    const unsigned short* __restrict__ vt,    // V^T global [(b*H+h)*64+d][T]
    unsigned short* __restrict__ out)         // [B*T][C] bf16
{
    __shared__ unsigned short Ks[2][128 * 64];   // [j][d], swizzled
    __shared__ unsigned short Vs[2][64 * 128];   // [d][j], swizzled

    const int idx = blockIdx.x;
    const int bh  = idx & 63;                 // b*16 + h
    const int qp  = idx >> 6;                 // 0..7
    const int b   = bh >> 4;
    const int h   = bh & 15;
    const int qtA = qp;
    const int qtB = 15 - qp;

    const int tid  = threadIdx.x;
    const int lane = tid & 63;
    const int w    = tid >> 6;
    const int l31  = lane & 31;
    const int hi   = lane >> 5;

    const int qwA = qtA * 128 + w * 32;
    const int qgA = qwA + l31;
    const int qwB = qtB * 128 + w * 32;
    const int qgB = qwB + l31;

    // Q fragments
    bf16x8 aqA[4], aqB[4];
    {
        const unsigned short* qpA = &qkv[(size_t)(b * T_ + qgA) * QKV_N + h * HS + hi * 8];
        const unsigned short* qpB = &qkv[(size_t)(b * T_ + qgB) * QKV_N + h * HS + hi * 8];
        #pragma unroll
        for (int kc = 0; kc < 4; ++kc) {
            aqA[kc] = *reinterpret_cast<const bf16x8*>(qpA + kc * 16);
            aqB[kc] = *reinterpret_cast<const bf16x8*>(qpB + kc * 16);
        }
    }

    f32x16 accA0 = {}, accA1 = {}, accB0 = {}, accB1 = {};
    float mA = -INFINITY, lA = 0.f, mB = -INFINITY, lB = 0.f;

    const float SCALE = 0.18033688011112042f;  // 0.125 * log2(e)

    auto stageKV = [&](int buf, int it) {
        #pragma unroll
        for (int n = 0; n < 4; ++n) {
            const int r  = n * 32 + (tid >> 3);
            const int sk = ((tid & 7) ^ (r & 7)) * 8;
            gload16(&qkv[(size_t)(b * T_ + it * 128 + r) * QKV_N + C_ + h * HS + sk],
                    &Ks[buf][(n * 256 + tid) * 8]);
        }
        #pragma unroll
        for (int n = 0; n < 4; ++n) {
            const int d  = n * 16 + (tid >> 4);
            const int sv = ((tid & 15) ^ (d & 7)) * 8;
            gload16(&vt[((size_t)(bh * HS + d)) * T_ + it * 128 + sv],
                    &Vs[buf][(n * 256 + tid) * 8]);
        }
    };

    auto process = [&](const unsigned short* Kb, const unsigned short* Vb,
                       const bf16x8* aq, f32x16& a0, f32x16& a1,
                       float& mval, float& lval, int qw, int qg,
                       int sub, int kbase) {
        // ---- S^T = K @ Q^T (two 32-j tiles within this 64 half) ----
        f32x16 st0 = {}, st1 = {};
        #pragma unroll
        for (int kc = 0; kc < 4; ++kc) {
            const int bo = kc * 32 + hi * 16;          // byte offset in 128B K row
            const int r0 = sub * 64 + l31;
            const bf16x8 ak0 = *reinterpret_cast<const bf16x8*>(
                &Kb[r0 * 64 + ((bo ^ ((r0 & 7) << 4)) >> 1)]);
            st0 = __builtin_amdgcn_mfma_f32_32x32x16_bf16(ak0, aq[kc], st0, 0, 0, 0);
            const int r1 = r0 + 32;
            const bf16x8 ak1 = *reinterpret_cast<const bf16x8*>(
                &Kb[r1 * 64 + ((bo ^ ((r1 & 7) << 4)) >> 1)]);
            st1 = __builtin_amdgcn_mfma_f32_32x32x16_bf16(ak1, aq[kc], st1, 0, 0, 0);
        }

        // ---- scale + causal mask (exp2 space) ----
        float p[32];
        if (kbase + 63 > qw) {
            #pragma unroll
            for (int r = 0; r < 16; ++r) {
                const int j0 = kbase + (r & 3) + 8 * (r >> 2) + 4 * hi;
                p[r]      = (j0      <= qg) ? st0[r] * SCALE : -INFINITY;
                p[r + 16] = (j0 + 32 <= qg) ? st1[r] * SCALE : -INFINITY;
            }
        } else {
            #pragma unroll
            for (int r = 0; r < 16; ++r) {
                p[r]      = st0[r] * SCALE;
                p[r + 16] = st1[r] * SCALE;
            }
        }

        // ---- online softmax, per-lane (q = lane&31) ----
        float tm = p[0];
        #pragma unroll
        for (int r = 1; r < 32; ++r) tm = fmaxf(tm, p[r]);
        tm = fmaxf(tm, __shfl_xor(tm, 32));

        const bool upd = (tm > mval + 8.f);          // defer-max THR=8 (log2)
        if (__ballot(upd)) {
            const float nm = upd ? tm : mval;
            const float sf = exp2f(mval - nm);
            lval *= sf;
            #pragma unroll
            for (int r = 0; r < 16; ++r) { a0[r] *= sf; a1[r] *= sf; }
            mval = nm;
        }

        float rs = 0.f;
        #pragma unroll
        for (int r = 0; r < 32; ++r) { p[r] = exp2f(p[r] - mval); rs += p[r]; }
        rs += __shfl_xor(rs, 32);
        lval += rs;

        // ---- P fragments + PV: O^T += Vt @ P ----
        #pragma unroll
        for (int jt = 0; jt < 2; ++jt) {
            #pragma unroll
            for (int c = 0; c < 2; ++c) {
                const int base = jt * 16 + c * 8;
                const unsigned pa = cvtpk_bf16(p[base + 0], p[base + 1]);
                const unsigned pb = cvtpk_bf16(p[base + 2], p[base + 3]);
                const unsigned pc = cvtpk_bf16(p[base + 4], p[base + 5]);
                const unsigned pd = cvtpk_bf16(p[base + 6], p[base + 7]);
                const unsigned pas = (unsigned)__shfl_xor((int)pa, 32);
                const unsigned pbs = (unsigned)__shfl_xor((int)pb, 32);
                const unsigned pcs = (unsigned)__shfl_xor((int)pc, 32);
                const unsigned pds = (unsigned)__shfl_xor((int)pd, 32);
                int4 bw;
                bw.x = (int)(hi ? pcs : pa);
                bw.y = (int)(hi ? pds : pb);
                bw.z = (int)(hi ? pc  : pas);
                bw.w = (int)(hi ? pd  : pbs);
                const bf16x8 bfrag = __builtin_bit_cast(bf16x8, bw);

                const int lslot = sub * 8 + (jt * 2 + c) * 2 + hi;  // 16B slot in 256B Vs row
                const int d0 = l31;
                const bf16x8 av0 = *reinterpret_cast<const bf16x8*>(
                    &Vb[d0 * 128 + (lslot ^ (d0 & 7)) * 8]);
                a0 = __builtin_amdgcn_mfma_f32_32x32x16_bf16(av0, bfrag, a0, 0, 0, 0);
                const int d1 = 32 + l31;
                const bf16x8 av1 = *reinterpret_cast<const bf16x8*>(
                    &Vb[d1 * 128 + (lslot ^ (d1 & 7)) * 8]);
                a1 = __builtin_amdgcn_mfma_f32_32x32x16_bf16(av1, bfrag, a1, 0, 0, 0);
            }
        }
    };

    const int nIter = qtB + 1;                       // 128-wide k chunks
    stageKV(0, 0);
    for (int it = 0; it < nIter; ++it) {
        const int cur = it & 1;
        __builtin_amdgcn_sched_barrier(0);
        if (it + 1 < nIter) {
            stageKV(cur ^ 1, it + 1);
            WAIT_VMCNT_8();
        } else {
            WAIT_VMCNT_0();
        }
        __builtin_amdgcn_s_barrier();
        __builtin_amdgcn_sched_barrier(0);

        const unsigned short* Kb = &Ks[cur][0];
        const unsigned short* Vb = &Vs[cur][0];
        #pragma unroll
        for (int sub = 0; sub < 2; ++sub) {
            const int kbase = it * 128 + sub * 64;
            if (kbase <= qwA + 31)
                process(Kb, Vb, aqA, accA0, accA1, mA, lA, qwA, qgA, sub, kbase);
            if (kbase <= qwB + 31)
                process(Kb, Vb, aqB, accB0, accB1, mB, lB, qwB, qgB, sub, kbase);
        }
        __builtin_amdgcn_sched_barrier(0);
        __builtin_amdgcn_s_barrier();
    }

    // ---- write O = acc^T / l ----
    {
        const float inv = 1.0f / lA;
        unsigned short* orow = &out[(size_t)(b * T_ + qgA) * C_ + h * HS];
        #pragma unroll
        for (int g = 0; g < 4; ++g) {
            uint2 wv;
            wv.x = cvtpk_bf16(accA0[4 * g + 0] * inv, accA0[4 * g + 1] * inv);
            wv.y = cvtpk_bf16(accA0[4 * g + 2] * inv, accA0[4 * g + 3] * inv);
            *reinterpret_cast<uint2*>(&orow[8 * g + 4 * hi]) = wv;
            uint2 wv1;
            wv1.x = cvtpk_bf16(accA1[4 * g + 0] * inv, accA1[4 * g + 1] * inv);
            wv1.y = cvtpk_bf16(accA1[4 * g + 2] * inv, accA1[4 * g + 3] * inv);
            *reinterpret_cast<uint2*>(&orow[32 + 8 * g + 4 * hi]) = wv1;
        }
    }
    {
        const float inv = 1.0f / lB;
        unsigned short* orow = &out[(size_t)(b * T_ + qgB) * C_ + h * HS];
        #pragma unroll
        for (int g = 0; g < 4; ++g) {
            uint2 wv;
            wv.x = cvtpk_bf16(accB0[4 * g + 0] * inv, accB0[4 * g + 1] * inv);
            wv.y = cvtpk_bf16(accB0[4 * g + 2] * inv, accB0[4 * g + 3] * inv);
            *reinterpret_cast<uint2*>(&orow[8 * g + 4 * hi]) = wv;
            uint2 wv1;
            wv1.x = cvtpk_bf16(accB1[4 * g + 0] * inv, accB1[4 * g + 1] * inv);
            wv1.y = cvtpk_bf16(accB1[4 * g + 2] * inv, accB1[4 * g + 3] * inv);
            *reinterpret_cast<uint2*>(&orow[32 + 8 * g + 4 * hi]) = wv1;
        }
    }
}

// ---------------------------------------------------------------------------
extern "C" void kernel_launch(void* const* d_in, const int* in_sizes, int n_in,
                              void* d_out, int out_size, void* d_ws, size_t ws_size,
                              hipStream_t stream)
{
    const float* x    = (const float*)d_in[0];   // [B,T,C]
    const float* Wqkv = (const float*)d_in[1];   // [C,3C]
    const float* bqkv = (const float*)d_in[2];   // [3C]
    const float* Wout = (const float*)d_in[3];   // [C,C]
    const float* bout = (const float*)d_in[4];   // [C]
    float* out = (float*)d_out;                  // [B,T,C] fp32

    char* ws = (char*)d_ws;
    unsigned short* qkvb  = (unsigned short*)ws;                       // 50,331,648
    unsigned short* xb    = (unsigned short*)(ws + 50331648);          // 16,777,216
    unsigned short* attnb = (unsigned short*)(ws + 67108864);          // 16,777,216
    unsigned short* vt_g  = (unsigned short*)(ws + 83886080);          // 16,777,216
    unsigned short* Wqkvt = (unsigned short*)(ws + 100663296);         //  6,291,456
    unsigned short* Woutt = (unsigned short*)(ws + 106954752);         //  2,097,152
    float2* tab           = (float2*)(ws + 109051904);                 //    524,288

    // 1) fused prep (cast + rope table) and fused weight transposes
    prep_kernel<<<4352, 256, 0, stream>>>(x, xb, tab);
    wtrans_kernel<<<4096, 256, 0, stream>>>(Wqkv, Wout, Wqkvt, Woutt);

    // 2) QKV projection, fused RoPE (q,k cols) + fused V^T (v cols)
    //    grid = 64 x 24 = 1536 blocks, XCD-region map
    gemm_mfma_kernel<QKV_N, C_, true, true, true>
        <<<(M_ / 128) * (QKV_N / 128), 256, 0, stream>>>(
        xb, Wqkvt, bqkv, tab, qkvb, vt_g, QKV_N / 128, M_ / 128);

    // 3) attention -> attnb [B,T,C] bf16 (paired causal q-tiles, pipelined)
    attn_mfma4_kernel<<<B_ * H_ * (T_ / 256), 256, 0, stream>>>(qkvb, vt_g, attnb);

    // 4) output projection (fp32 out): 64 x 8 = 512 blocks, XCD-region map
    gemm_mfma_kernel<C_, C_, false, false, false>
        <<<(M_ / 128) * (C_ / 128), 256, 0, stream>>>(
        attnb, Woutt, bout, nullptr, out, nullptr, C_ / 128, M_ / 128);
}

// Round 11
// 169.757 us; speedup vs baseline: 1.4506x; 1.1170x over previous
//
#include <hip/hip_runtime.h>
#include <math.h>

// Problem constants (B=4, T=2048, C=1024, H=16, hs=64)
#define B_   4
#define T_   2048
#define C_   1024
#define H_   16
#define HS   64
#define HALF 32
#define QKV_N (3 * C_)      // 3072
#define M_    (B_ * T_)     // 8192

using bf16x8 = __attribute__((ext_vector_type(8))) short;
using f32x4  = __attribute__((ext_vector_type(4))) float;
using f32x16 = __attribute__((ext_vector_type(16))) float;
using u16x4  = __attribute__((ext_vector_type(4))) unsigned short;
using u32x2  = __attribute__((ext_vector_type(2))) unsigned int;

__device__ __forceinline__ unsigned short f2bf(float f) {
    unsigned u = __builtin_bit_cast(unsigned, f);
    u = (u + 0x7FFFu + ((u >> 16) & 1u)) >> 16;
    return (unsigned short)u;
}
__device__ __forceinline__ float bf2f(unsigned short b) {
    return __builtin_bit_cast(float, (unsigned)b << 16);
}
__device__ __forceinline__ unsigned cvtpk_bf16(float lo, float hi_) {
    unsigned r;
    asm("v_cvt_pk_bf16_f32 %0, %1, %2" : "=v"(r) : "v"(lo), "v"(hi_));
    return r;
}
__device__ __forceinline__ void gload16(const void* g, void* l) {
    __builtin_amdgcn_global_load_lds(
        (const __attribute__((address_space(1))) unsigned int*)g,
        (__attribute__((address_space(3))) unsigned int*)l, 16, 0, 0);
}
#define WAIT_VMCNT_8() asm volatile("s_waitcnt vmcnt(8)" ::: "memory")
#define WAIT_VMCNT_0() asm volatile("s_waitcnt vmcnt(0)" ::: "memory")

// raw v_exp_f32 (2^x) — exp2f without fast-math lowers to guarded libm.
#if __has_builtin(__builtin_amdgcn_exp2f)
#define EXP2(x) __builtin_amdgcn_exp2f(x)
#else
#define EXP2(x) exp2f(x)
#endif
#define FMAX3(a, b, c) fmaxf(fmaxf((a), (b)), (c))

#define QSCALE 0.18033688011112042f   // 0.125 * log2(e), folded into Q

// ---------------------------------------------------------------------------
// prep: blocks [0,4096): fp32->bf16 cast of x; blocks [4096,4352): RoPE table.
// ---------------------------------------------------------------------------
__global__ __launch_bounds__(256) void prep_kernel(
    const float* __restrict__ in, unsigned short* __restrict__ out,
    float2* __restrict__ tab)
{
    const int bid = blockIdx.x;
    if (bid < 4096) {
        const size_t i = ((size_t)bid * 256 + threadIdx.x) * 8;
        const float4 a = *reinterpret_cast<const float4*>(&in[i]);
        const float4 b = *reinterpret_cast<const float4*>(&in[i + 4]);
        bf16x8 v;
        v[0] = f2bf(a.x); v[1] = f2bf(a.y); v[2] = f2bf(a.z); v[3] = f2bf(a.w);
        v[4] = f2bf(b.x); v[5] = f2bf(b.y); v[6] = f2bf(b.z); v[7] = f2bf(b.w);
        *reinterpret_cast<bf16x8*>(&out[i]) = v;
    } else {
        const int idx = (bid - 4096) * 256 + threadIdx.x;   // 0 .. T_*HALF-1
        const int t = idx / HALF;
        const int i = idx % HALF;
        const float theta = powf(10000.0f, -(float)i / (float)HALF);
        const float ang = (float)t * theta;
        float sn, cs;
        sincosf(ang, &sn, &cs);
        tab[idx] = make_float2(sn, cs);
    }
}

// ---------------------------------------------------------------------------
// wtrans: both weight transposes in one dispatch.
// ---------------------------------------------------------------------------
__global__ __launch_bounds__(256) void wtrans_kernel(
    const float* __restrict__ Wqkv, const float* __restrict__ Wout,
    unsigned short* __restrict__ Wqkvt, unsigned short* __restrict__ Woutt)
{
    __shared__ float tile[32][33];
    const int bid = blockIdx.x;
    const float* W;
    unsigned short* Wt;
    int N, k0, n0;
    if (bid < 3072) {
        W = Wqkv; Wt = Wqkvt; N = QKV_N;
        n0 = (bid % 96) * 32; k0 = (bid / 96) * 32;
    } else {
        const int r2 = bid - 3072;
        W = Wout; Wt = Woutt; N = C_;
        n0 = (r2 % 32) * 32; k0 = (r2 / 32) * 32;
    }
    const int K = C_;
    const int r = threadIdx.x / 32;
    const int c = threadIdx.x % 32;
    #pragma unroll
    for (int it = 0; it < 4; ++it)
        tile[r + it * 8][c] = W[(size_t)(k0 + r + it * 8) * N + n0 + c];
    __syncthreads();
    #pragma unroll
    for (int it = 0; it < 4; ++it)
        Wt[(size_t)(n0 + r + it * 8) * K + k0 + c] = f2bf(tile[c][r + it * 8]);
}

// ---------------------------------------------------------------------------
// bf16 MFMA GEMM (m97 structure; compile-time dims; strength-reduced addrs).
// 128x128 tile, BK=32, 256 threads = 4 waves (2x2), 2-barrier loop,
// global_load_lds width-16 staging, linear LDS, 4x2 XCD-region swizzle.
// VSPLIT: v-column blocks write transposed into vt. ROPE: fused rotation on
// q,k cols; q cols additionally pre-scaled by QSCALE (attention folds it out).
// ---------------------------------------------------------------------------
template <int N, int K, bool BF16OUT, bool ROPE, bool VSPLIT>
__global__ __launch_bounds__(256, 4) void gemm_mfma_kernel(
    const unsigned short* __restrict__ A, const unsigned short* __restrict__ Bt,
    const float* __restrict__ bias, const float2* __restrict__ tab,
    void* __restrict__ Cout, unsigned short* __restrict__ vt, int nbx, int nby)
{
    __shared__ unsigned short As[128 * 32];
    __shared__ unsigned short Bs[128 * 32];

    const int tid  = threadIdx.x;
    const int lane = tid & 63;
    const int wave = tid >> 6;
    const int wr   = wave >> 1;
    const int wc   = wave & 1;
    const int l15  = lane & 15;
    const int l4   = lane >> 4;

    // ---- 4x2 XCD-region block swizzle ----
    const int bid  = blockIdx.x;
    const int xcd  = bid & 7;
    const int w    = bid >> 3;
    const int cpr  = nbx >> 1;
    const int rpr  = nby >> 2;
    const int by   = ((xcd >> 1) * rpr) + (w / cpr);
    const int bx   = ((xcd & 1) * cpr) + (w % cpr);
    const int row0 = by * 128;
    const int col0 = bx * 128;

    f32x4 acc[4][4] = {};

    const int ar = tid >> 2, ac = (tid & 3) * 8;
    const unsigned short* ap = &A[(size_t)(row0 + ar) * K + ac];
    const unsigned short* bp = &Bt[(size_t)(col0 + ar) * K + ac];

    for (int it = 0; it < K / 32; ++it) {
        gload16(ap,          &As[tid * 8]);
        gload16(ap + 64 * K, &As[(tid + 256) * 8]);
        gload16(bp,          &Bs[tid * 8]);
        gload16(bp + 64 * K, &Bs[(tid + 256) * 8]);
        __syncthreads();

        bf16x8 a[4], b[4];
        #pragma unroll
        for (int mi = 0; mi < 4; ++mi)
            a[mi] = *reinterpret_cast<const bf16x8*>(
                &As[(wr * 64 + mi * 16 + l15) * 32 + l4 * 8]);
        #pragma unroll
        for (int nj = 0; nj < 4; ++nj)
            b[nj] = *reinterpret_cast<const bf16x8*>(
                &Bs[(wc * 64 + nj * 16 + l15) * 32 + l4 * 8]);
        #pragma unroll
        for (int mi = 0; mi < 4; ++mi)
            #pragma unroll
            for (int nj = 0; nj < 4; ++nj)
                acc[mi][nj] = __builtin_amdgcn_mfma_f32_16x16x32_bf16(
                    a[mi], b[nj], acc[mi][nj], 0, 0, 0);
        __syncthreads();
        ap += 32;
        bp += 32;
    }

    float bv[4];
    #pragma unroll
    for (int nj = 0; nj < 4; ++nj)
        bv[nj] = bias[col0 + wc * 64 + nj * 16 + l15];

    if (VSPLIT && col0 >= 2 * C_) {
        #pragma unroll
        for (int mi = 0; mi < 4; ++mi) {
            const int rowb = row0 + wr * 64 + mi * 16 + l4 * 4;
            const int b  = rowb >> 11;
            const int t0 = rowb & (T_ - 1);
            #pragma unroll
            for (int nj = 0; nj < 4; ++nj) {
                const int cv = col0 - 2 * C_ + wc * 64 + nj * 16 + l15;
                u16x4 pack;
                #pragma unroll
                for (int r = 0; r < 4; ++r)
                    pack[r] = f2bf(acc[mi][nj][r] + bv[nj]);
                *reinterpret_cast<u16x4*>(
                    &vt[((size_t)(b * H_ * HS + cv)) * T_ + t0]) = pack;
            }
        }
        return;
    }

    const bool doRope = ROPE && (col0 < 2 * C_);
    const bool doScaleQ = ROPE && (col0 < C_);   // pre-scale q for attention

    #pragma unroll
    for (int mi = 0; mi < 4; ++mi) {
        #pragma unroll
        for (int r = 0; r < 4; ++r) {
            const int row = row0 + wr * 64 + mi * 16 + l4 * 4 + r;
            const int t   = row & (T_ - 1);
            #pragma unroll
            for (int nj = 0; nj < 4; ++nj) {
                const int col = col0 + wc * 64 + nj * 16 + l15;
                float v = acc[mi][nj][r] + bv[nj];
                if (doRope) {
                    const float partner = __shfl_xor(v, 1);
                    const float2 sc = tab[t * HALF + ((col & 63) >> 1)];
                    v = v * sc.y + ((col & 1) ? partner : -partner) * sc.x;
                }
                if (doScaleQ) v *= QSCALE;
                if (BF16OUT)
                    ((unsigned short*)Cout)[(size_t)row * N + col] = f2bf(v);
                else
                    ((float*)Cout)[(size_t)row * N + col] = v;
            }
        }
    }
}

// ---------------------------------------------------------------------------
// Flash attention v5: 32x32 MFMA, swapped operands, PAIRED causal q-tiles,
// double-buffered K/V with counted vmcnt(8) prefetch.
// R10 changes: merged 128-j softmax pass (single max/defer/rescale/sum per
// staged chunk, in place in S regs), raw v_exp_f32 via builtin, Q pre-scaled
// in GEMM (no per-score multiply), permlane32_swap packing, setprio on MFMA.
// ---------------------------------------------------------------------------
__global__ __launch_bounds__(256, 2) void attn_mfma5_kernel(
    const unsigned short* __restrict__ qkv,   // roped+scaled qkv, bf16
    const unsigned short* __restrict__ vt,    // V^T global [(b*H+h)*64+d][T]
    unsigned short* __restrict__ out)         // [B*T][C] bf16
{
    __shared__ unsigned short Ks[2][128 * 64];   // [j][d], swizzled
    __shared__ unsigned short Vs[2][64 * 128];   // [d][j], swizzled

    const int idx = blockIdx.x;
    const int bh  = idx & 63;                 // b*16 + h
    const int qp  = idx >> 6;                 // 0..7
    const int b   = bh >> 4;
    const int h   = bh & 15;
    const int qtA = qp;
    const int qtB = 15 - qp;

    const int tid  = threadIdx.x;
    const int lane = tid & 63;
    const int w    = tid >> 6;
    const int l31  = lane & 31;
    const int hi   = lane >> 5;

    const int qwA = qtA * 128 + w * 32;
    const int qgA = qwA + l31;
    const int qwB = qtB * 128 + w * 32;
    const int qgB = qwB + l31;

    // Q fragments (pre-scaled by QSCALE in the projection epilogue)
    bf16x8 aqA[4], aqB[4];
    {
        const unsigned short* qpA = &qkv[(size_t)(b * T_ + qgA) * QKV_N + h * HS + hi * 8];
        const unsigned short* qpB = &qkv[(size_t)(b * T_ + qgB) * QKV_N + h * HS + hi * 8];
        #pragma unroll
        for (int kc = 0; kc < 4; ++kc) {
            aqA[kc] = *reinterpret_cast<const bf16x8*>(qpA + kc * 16);
            aqB[kc] = *reinterpret_cast<const bf16x8*>(qpB + kc * 16);
        }
    }

    f32x16 accA0 = {}, accA1 = {}, accB0 = {}, accB1 = {};
    float mA = -INFINITY, lA = 0.f, mB = -INFINITY, lB = 0.f;

    auto stageKV = [&](int buf, int it) {
        #pragma unroll
        for (int n = 0; n < 4; ++n) {
            const int r  = n * 32 + (tid >> 3);
            const int sk = ((tid & 7) ^ (r & 7)) * 8;
            gload16(&qkv[(size_t)(b * T_ + it * 128 + r) * QKV_N + C_ + h * HS + sk],
                    &Ks[buf][(n * 256 + tid) * 8]);
        }
        #pragma unroll
        for (int n = 0; n < 4; ++n) {
            const int d  = n * 16 + (tid >> 4);
            const int sv = ((tid & 15) ^ (d & 7)) * 8;
            gload16(&vt[((size_t)(bh * HS + d)) * T_ + it * 128 + sv],
                    &Vs[buf][(n * 256 + tid) * 8]);
        }
    };

    // merged 128-j processing
    auto process = [&](const unsigned short* Kb, const unsigned short* Vb,
                       const bf16x8* aq, f32x16& a0, f32x16& a1,
                       float& mval, float& lval, int qw, int qg, int kbase) {
        // ---- S^T = K @ Q^T : four 32-j tiles covering 128 j ----
        f32x16 s[4] = {};
        __builtin_amdgcn_s_setprio(1);
        #pragma unroll
        for (int kc = 0; kc < 4; ++kc) {
            const int bo = kc * 32 + hi * 16;          // byte offset in 128B K row
            #pragma unroll
            for (int g = 0; g < 4; ++g) {
                const int rj = g * 32 + l31;
                const bf16x8 ak = *reinterpret_cast<const bf16x8*>(
                    &Kb[rj * 64 + ((bo ^ ((rj & 7) << 4)) >> 1)]);
                s[g] = __builtin_amdgcn_mfma_f32_32x32x16_bf16(ak, aq[kc], s[g], 0, 0, 0);
            }
        }
        __builtin_amdgcn_s_setprio(0);

        // ---- causal mask (Q pre-scaled: s already in log2-exp space) ----
        if (kbase + 127 > qw) {
            #pragma unroll
            for (int g = 0; g < 4; ++g) {
                #pragma unroll
                for (int r = 0; r < 16; ++r) {
                    const int j0 = kbase + g * 32 + (r & 3) + 8 * (r >> 2) + 4 * hi;
                    if (j0 > qg) s[g][r] = -INFINITY;
                }
            }
        }

        // ---- merged online softmax over 128 j, per-lane (q = lane&31) ----
        float tg[4];
        #pragma unroll
        for (int g = 0; g < 4; ++g) {
            const float v0 = FMAX3(s[g][0],  s[g][1],  s[g][2]);
            const float v1 = FMAX3(s[g][3],  s[g][4],  s[g][5]);
            const float v2 = FMAX3(s[g][6],  s[g][7],  s[g][8]);
            const float v3 = FMAX3(s[g][9],  s[g][10], s[g][11]);
            const float v4 = FMAX3(s[g][12], s[g][13], s[g][14]);
            tg[g] = fmaxf(FMAX3(v0, v1, v2), FMAX3(v3, v4, s[g][15]));
        }
        float tm = fmaxf(fmaxf(tg[0], tg[1]), fmaxf(tg[2], tg[3]));
        tm = fmaxf(tm, __shfl_xor(tm, 32));

        const bool upd = (tm > mval + 8.f);          // defer-max THR=8 (log2)
        if (__ballot(upd)) {
            const float nm = upd ? tm : mval;
            const float sf = EXP2(mval - nm);
            lval *= sf;
            #pragma unroll
            for (int r = 0; r < 16; ++r) { a0[r] *= sf; a1[r] *= sf; }
            mval = nm;
        }

        float rs0 = 0.f, rs1 = 0.f, rs2 = 0.f, rs3 = 0.f;
        #pragma unroll
        for (int r = 0; r < 16; ++r) {
            s[0][r] = EXP2(s[0][r] - mval); rs0 += s[0][r];
            s[1][r] = EXP2(s[1][r] - mval); rs1 += s[1][r];
            s[2][r] = EXP2(s[2][r] - mval); rs2 += s[2][r];
            s[3][r] = EXP2(s[3][r] - mval); rs3 += s[3][r];
        }
        float rs = (rs0 + rs1) + (rs2 + rs3);
        rs += __shfl_xor(rs, 32);
        lval += rs;

        // ---- P fragments + PV: O^T += Vt @ P (two 64-j subtiles) ----
        #pragma unroll
        for (int g2 = 0; g2 < 2; ++g2) {
            #pragma unroll
            for (int jt = 0; jt < 2; ++jt) {
                const int g = g2 * 2 + jt;
                #pragma unroll
                for (int c = 0; c < 2; ++c) {
                    const int e = c * 8;
                    const unsigned pa = cvtpk_bf16(s[g][e + 0], s[g][e + 1]);
                    const unsigned pb = cvtpk_bf16(s[g][e + 2], s[g][e + 3]);
                    const unsigned pc = cvtpk_bf16(s[g][e + 4], s[g][e + 5]);
                    const unsigned pd = cvtpk_bf16(s[g][e + 6], s[g][e + 7]);
                    int4 bw;
#if __has_builtin(__builtin_amdgcn_permlane32_swap)
                    const u32x2 rx = __builtin_amdgcn_permlane32_swap(pa, pc, false, false);
                    const u32x2 ry = __builtin_amdgcn_permlane32_swap(pb, pd, false, false);
                    bw.x = (int)rx[0]; bw.y = (int)ry[0];
                    bw.z = (int)rx[1]; bw.w = (int)ry[1];
#else
                    const unsigned pas = (unsigned)__shfl_xor((int)pa, 32);
                    const unsigned pbs = (unsigned)__shfl_xor((int)pb, 32);
                    const unsigned pcs = (unsigned)__shfl_xor((int)pc, 32);
                    const unsigned pds = (unsigned)__shfl_xor((int)pd, 32);
                    bw.x = (int)(hi ? pcs : pa);
                    bw.y = (int)(hi ? pds : pb);
                    bw.z = (int)(hi ? pc  : pas);
                    bw.w = (int)(hi ? pd  : pbs);
#endif
                    const bf16x8 bfrag = __builtin_bit_cast(bf16x8, bw);

                    const int lslot = g2 * 8 + (jt * 2 + c) * 2 + hi;
                    const int d0 = l31;
                    const bf16x8 av0 = *reinterpret_cast<const bf16x8*>(
                        &Vb[d0 * 128 + (lslot ^ (d0 & 7)) * 8]);
                    const int d1 = 32 + l31;
                    const bf16x8 av1 = *reinterpret_cast<const bf16x8*>(
                        &Vb[d1 * 128 + (lslot ^ (d1 & 7)) * 8]);
                    __builtin_amdgcn_s_setprio(1);
                    a0 = __builtin_amdgcn_mfma_f32_32x32x16_bf16(av0, bfrag, a0, 0, 0, 0);
                    a1 = __builtin_amdgcn_mfma_f32_32x32x16_bf16(av1, bfrag, a1, 0, 0, 0);
                    __builtin_amdgcn_s_setprio(0);
                }
            }
        }
    };

    const int nIter = qtB + 1;                       // 128-wide k chunks
    stageKV(0, 0);
    for (int it = 0; it < nIter; ++it) {
        const int cur = it & 1;
        __builtin_amdgcn_sched_barrier(0);
        if (it + 1 < nIter) {
            stageKV(cur ^ 1, it + 1);
            WAIT_VMCNT_8();
        } else {
            WAIT_VMCNT_0();
        }
        __builtin_amdgcn_s_barrier();
        __builtin_amdgcn_sched_barrier(0);

        const unsigned short* Kb = &Ks[cur][0];
        const unsigned short* Vb = &Vs[cur][0];
        const int kbase = it * 128;
        if (kbase <= qwA + 31)
            process(Kb, Vb, aqA, accA0, accA1, mA, lA, qwA, qgA, kbase);
        if (kbase <= qwB + 31)
            process(Kb, Vb, aqB, accB0, accB1, mB, lB, qwB, qgB, kbase);
        __builtin_amdgcn_sched_barrier(0);
        __builtin_amdgcn_s_barrier();
    }

    // ---- write O = acc^T / l ----
    {
        const float inv = 1.0f / lA;
        unsigned short* orow = &out[(size_t)(b * T_ + qgA) * C_ + h * HS];
        #pragma unroll
        for (int g = 0; g < 4; ++g) {
            uint2 wv;
            wv.x = cvtpk_bf16(accA0[4 * g + 0] * inv, accA0[4 * g + 1] * inv);
            wv.y = cvtpk_bf16(accA0[4 * g + 2] * inv, accA0[4 * g + 3] * inv);
            *reinterpret_cast<uint2*>(&orow[8 * g + 4 * hi]) = wv;
            uint2 wv1;
            wv1.x = cvtpk_bf16(accA1[4 * g + 0] * inv, accA1[4 * g + 1] * inv);
            wv1.y = cvtpk_bf16(accA1[4 * g + 2] * inv, accA1[4 * g + 3] * inv);
            *reinterpret_cast<uint2*>(&orow[32 + 8 * g + 4 * hi]) = wv1;
        }
    }
    {
        const float inv = 1.0f / lB;
        unsigned short* orow = &out[(size_t)(b * T_ + qgB) * C_ + h * HS];
        #pragma unroll
        for (int g = 0; g < 4; ++g) {
            uint2 wv;
            wv.x = cvtpk_bf16(accB0[4 * g + 0] * inv, accB0[4 * g + 1] * inv);
            wv.y = cvtpk_bf16(accB0[4 * g + 2] * inv, accB0[4 * g + 3] * inv);
            *reinterpret_cast<uint2*>(&orow[8 * g + 4 * hi]) = wv;
            uint2 wv1;
            wv1.x = cvtpk_bf16(accB1[4 * g + 0] * inv, accB1[4 * g + 1] * inv);
            wv1.y = cvtpk_bf16(accB1[4 * g + 2] * inv, accB1[4 * g + 3] * inv);
            *reinterpret_cast<uint2*>(&orow[32 + 8 * g + 4 * hi]) = wv1;
        }
    }
}

// ---------------------------------------------------------------------------
extern "C" void kernel_launch(void* const* d_in, const int* in_sizes, int n_in,
                              void* d_out, int out_size, void* d_ws, size_t ws_size,
                              hipStream_t stream)
{
    const float* x    = (const float*)d_in[0];   // [B,T,C]
    const float* Wqkv = (const float*)d_in[1];   // [C,3C]
    const float* bqkv = (const float*)d_in[2];   // [3C]
    const float* Wout = (const float*)d_in[3];   // [C,C]
    const float* bout = (const float*)d_in[4];   // [C]
    float* out = (float*)d_out;                  // [B,T,C] fp32

    char* ws = (char*)d_ws;
    unsigned short* qkvb  = (unsigned short*)ws;                       // 50,331,648
    unsigned short* xb    = (unsigned short*)(ws + 50331648);          // 16,777,216
    unsigned short* attnb = (unsigned short*)(ws + 67108864);          // 16,777,216
    unsigned short* vt_g  = (unsigned short*)(ws + 83886080);          // 16,777,216
    unsigned short* Wqkvt = (unsigned short*)(ws + 100663296);         //  6,291,456
    unsigned short* Woutt = (unsigned short*)(ws + 106954752);         //  2,097,152
    float2* tab           = (float2*)(ws + 109051904);                 //    524,288

    // 1) fused prep (cast + rope table) and fused weight transposes
    prep_kernel<<<4352, 256, 0, stream>>>(x, xb, tab);
    wtrans_kernel<<<4096, 256, 0, stream>>>(Wqkv, Wout, Wqkvt, Woutt);

    // 2) QKV projection, fused RoPE + Q-prescale (q,k cols) + fused V^T (v cols)
    gemm_mfma_kernel<QKV_N, C_, true, true, true>
        <<<(M_ / 128) * (QKV_N / 128), 256, 0, stream>>>(
        xb, Wqkvt, bqkv, tab, qkvb, vt_g, QKV_N / 128, M_ / 128);

    // 3) attention -> attnb [B,T,C] bf16 (paired causal q-tiles, merged softmax)
    attn_mfma5_kernel<<<B_ * H_ * (T_ / 256), 256, 0, stream>>>(qkvb, vt_g, attnb);

    // 4) output projection (fp32 out): 64 x 8 = 512 blocks, XCD-region map
    gemm_mfma_kernel<C_, C_, false, false, false>
        <<<(M_ / 128) * (C_ / 128), 256, 0, stream>>>(
        attnb, Woutt, bout, nullptr, out, nullptr, C_ / 128, M_ / 128);
}

// Round 12
// 167.191 us; speedup vs baseline: 1.4728x; 1.0153x over previous
//
#include <hip/hip_runtime.h>
#include <math.h>

// Problem constants (B=4, T=2048, C=1024, H=16, hs=64)
#define B_   4
#define T_   2048
#define C_   1024
#define H_   16
#define HS   64
#define HALF 32
#define QKV_N (3 * C_)      // 3072
#define M_    (B_ * T_)     // 8192

using bf16x8 = __attribute__((ext_vector_type(8))) short;
using f32x4  = __attribute__((ext_vector_type(4))) float;
using f32x16 = __attribute__((ext_vector_type(16))) float;
using u16x4  = __attribute__((ext_vector_type(4))) unsigned short;
using u32x2  = __attribute__((ext_vector_type(2))) unsigned int;

__device__ __forceinline__ unsigned short f2bf(float f) {
    unsigned u = __builtin_bit_cast(unsigned, f);
    u = (u + 0x7FFFu + ((u >> 16) & 1u)) >> 16;
    return (unsigned short)u;
}
__device__ __forceinline__ float bf2f(unsigned short b) {
    return __builtin_bit_cast(float, (unsigned)b << 16);
}
__device__ __forceinline__ unsigned cvtpk_bf16(float lo, float hi_) {
    unsigned r;
    asm("v_cvt_pk_bf16_f32 %0, %1, %2" : "=v"(r) : "v"(lo), "v"(hi_));
    return r;
}
__device__ __forceinline__ void gload16(const void* g, void* l) {
    __builtin_amdgcn_global_load_lds(
        (const __attribute__((address_space(1))) unsigned int*)g,
        (__attribute__((address_space(3))) unsigned int*)l, 16, 0, 0);
}
#define WAIT_VMCNT_8() asm volatile("s_waitcnt vmcnt(8)" ::: "memory")
#define WAIT_VMCNT_4() asm volatile("s_waitcnt vmcnt(4)" ::: "memory")
#define WAIT_VMCNT_0() asm volatile("s_waitcnt vmcnt(0)" ::: "memory")

// raw v_exp_f32 (2^x) — exp2f without fast-math lowers to guarded libm.
#if __has_builtin(__builtin_amdgcn_exp2f)
#define EXP2(x) __builtin_amdgcn_exp2f(x)
#else
#define EXP2(x) exp2f(x)
#endif
#define FMAX3(a, b, c) fmaxf(fmaxf((a), (b)), (c))

#define QSCALE 0.18033688011112042f   // 0.125 * log2(e), folded into Q

// ---------------------------------------------------------------------------
// prep2: blocks [0,4096): fp32->bf16 cast of x
//        blocks [4096,4352): RoPE sin/cos table
//        blocks [4352,7424): Wqkv transpose+cast
//        blocks [7424,8448): Wout transpose+cast
// ---------------------------------------------------------------------------
__global__ __launch_bounds__(256) void prep2_kernel(
    const float* __restrict__ x, unsigned short* __restrict__ xb,
    float2* __restrict__ tab,
    const float* __restrict__ Wqkv, const float* __restrict__ Wout,
    unsigned short* __restrict__ Wqkvt, unsigned short* __restrict__ Woutt)
{
    __shared__ float tile[32][33];
    const int bid = blockIdx.x;
    if (bid < 4096) {
        const size_t i = ((size_t)bid * 256 + threadIdx.x) * 8;
        const float4 a = *reinterpret_cast<const float4*>(&x[i]);
        const float4 b = *reinterpret_cast<const float4*>(&x[i + 4]);
        bf16x8 v;
        v[0] = f2bf(a.x); v[1] = f2bf(a.y); v[2] = f2bf(a.z); v[3] = f2bf(a.w);
        v[4] = f2bf(b.x); v[5] = f2bf(b.y); v[6] = f2bf(b.z); v[7] = f2bf(b.w);
        *reinterpret_cast<bf16x8*>(&xb[i]) = v;
        return;
    }
    if (bid < 4352) {
        const int idx = (bid - 4096) * 256 + threadIdx.x;   // 0 .. T_*HALF-1
        const int t = idx / HALF;
        const int i = idx % HALF;
        const float theta = powf(10000.0f, -(float)i / (float)HALF);
        const float ang = (float)t * theta;
        float sn, cs;
        sincosf(ang, &sn, &cs);
        tab[idx] = make_float2(sn, cs);
        return;
    }
    // weight transposes
    const float* W;
    unsigned short* Wt;
    int N, k0, n0;
    if (bid < 7424) {
        const int r0 = bid - 4352;
        W = Wqkv; Wt = Wqkvt; N = QKV_N;
        n0 = (r0 % 96) * 32; k0 = (r0 / 96) * 32;
    } else {
        const int r0 = bid - 7424;
        W = Wout; Wt = Woutt; N = C_;
        n0 = (r0 % 32) * 32; k0 = (r0 / 32) * 32;
    }
    const int K = C_;
    const int r = threadIdx.x / 32;
    const int c = threadIdx.x % 32;
    #pragma unroll
    for (int it = 0; it < 4; ++it)
        tile[r + it * 8][c] = W[(size_t)(k0 + r + it * 8) * N + n0 + c];
    __syncthreads();
    #pragma unroll
    for (int it = 0; it < 4; ++it)
        Wt[(size_t)(n0 + r + it * 8) * K + k0 + c] = f2bf(tile[c][r + it * 8]);
}

// ---------------------------------------------------------------------------
// bf16 MFMA GEMM v11: m97 structure + granule-XOR LDS swizzle (conflict-free
// ds_read_b128) + BK=32 double-buffer with counted vmcnt(4).
// 128x128 tile, 256 threads = 4 waves (2x2), compile-time dims,
// strength-reduced pointers, 4 blocks/CU, 4x2 XCD-region swizzle.
// Swizzle: LDS row r (64B = 4 16B slots), slot s holds global k-chunk
// s ^ ((r>>1)&3); staged via inverse-swizzled global source, linear dest.
// 16-lane fragment reads then spread 2 lanes/granule (free, m136).
// ---------------------------------------------------------------------------
template <int N, int K, bool BF16OUT, bool ROPE, bool VSPLIT>
__global__ __launch_bounds__(256, 4) void gemm_mfma_kernel(
    const unsigned short* __restrict__ A, const unsigned short* __restrict__ Bt,
    const float* __restrict__ bias, const float2* __restrict__ tab,
    void* __restrict__ Cout, unsigned short* __restrict__ vt, int nbx, int nby)
{
    __shared__ unsigned short As[2][128 * 32];
    __shared__ unsigned short Bs[2][128 * 32];

    const int tid  = threadIdx.x;
    const int lane = tid & 63;
    const int wave = tid >> 6;
    const int wr   = wave >> 1;
    const int wc   = wave & 1;
    const int l15  = lane & 15;
    const int l4   = lane >> 4;

    // ---- 4x2 XCD-region block swizzle ----
    const int bid  = blockIdx.x;
    const int xcd  = bid & 7;
    const int w    = bid >> 3;
    const int cpr  = nbx >> 1;
    const int rpr  = nby >> 2;
    const int by   = ((xcd >> 1) * rpr) + (w / cpr);
    const int bx   = ((xcd & 1) * cpr) + (w % cpr);
    const int row0 = by * 128;
    const int col0 = bx * 128;

    f32x4 acc[4][4] = {};

    // staging: thread covers row ar (and ar+64), slot sl; source k-chunk
    // inverse-swizzled so LDS dest stays linear.
    const int ar  = tid >> 2;
    const int sl  = tid & 3;
    const int swz = (sl ^ ((ar >> 1) & 3)) * 8;
    const unsigned short* ap = &A[(size_t)(row0 + ar) * K + swz];
    const unsigned short* bp = &Bt[(size_t)(col0 + ar) * K + swz];

    auto stage = [&](int buf, int t) {
        const unsigned short* a0 = ap + t * 32;
        const unsigned short* b0 = bp + t * 32;
        gload16(a0,          &As[buf][tid * 8]);
        gload16(a0 + 64 * K, &As[buf][(tid + 256) * 8]);
        gload16(b0,          &Bs[buf][tid * 8]);
        gload16(b0 + 64 * K, &Bs[buf][(tid + 256) * 8]);
    };

    // hoisted, swizzled fragment read offsets (loop-invariant)
    int aoff[4], boff[4];
    #pragma unroll
    for (int mi = 0; mi < 4; ++mi) {
        const int lr = wr * 64 + mi * 16 + l15;
        aoff[mi] = lr * 32 + ((l4 ^ ((lr >> 1) & 3)) * 8);
    }
    #pragma unroll
    for (int nj = 0; nj < 4; ++nj) {
        const int lr = wc * 64 + nj * 16 + l15;
        boff[nj] = lr * 32 + ((l4 ^ ((lr >> 1) & 3)) * 8);
    }

    constexpr int nt = K / 32;
    stage(0, 0);

    for (int t = 0; t < nt; ++t) {
        const int cur = t & 1;
        if (t + 1 < nt) {
            stage(cur ^ 1, t + 1);   // next tile into alt buffer
            WAIT_VMCNT_4();          // tile t's 4 loads (oldest) have landed
        } else {
            WAIT_VMCNT_0();
        }
        __builtin_amdgcn_s_barrier();
        __builtin_amdgcn_sched_barrier(0);

        bf16x8 a[4], b[4];
        #pragma unroll
        for (int mi = 0; mi < 4; ++mi)
            a[mi] = *reinterpret_cast<const bf16x8*>(&As[cur][aoff[mi]]);
        #pragma unroll
        for (int nj = 0; nj < 4; ++nj)
            b[nj] = *reinterpret_cast<const bf16x8*>(&Bs[cur][boff[nj]]);
        #pragma unroll
        for (int mi = 0; mi < 4; ++mi)
            #pragma unroll
            for (int nj = 0; nj < 4; ++nj)
                acc[mi][nj] = __builtin_amdgcn_mfma_f32_16x16x32_bf16(
                    a[mi], b[nj], acc[mi][nj], 0, 0, 0);

        __builtin_amdgcn_sched_barrier(0);
        __builtin_amdgcn_s_barrier();   // all waves done reading tile t
    }

    float bv[4];
    #pragma unroll
    for (int nj = 0; nj < 4; ++nj)
        bv[nj] = bias[col0 + wc * 64 + nj * 16 + l15];

    if (VSPLIT && col0 >= 2 * C_) {
        #pragma unroll
        for (int mi = 0; mi < 4; ++mi) {
            const int rowb = row0 + wr * 64 + mi * 16 + l4 * 4;
            const int b  = rowb >> 11;
            const int t0 = rowb & (T_ - 1);
            #pragma unroll
            for (int nj = 0; nj < 4; ++nj) {
                const int cv = col0 - 2 * C_ + wc * 64 + nj * 16 + l15;
                u16x4 pack;
                #pragma unroll
                for (int r = 0; r < 4; ++r)
                    pack[r] = f2bf(acc[mi][nj][r] + bv[nj]);
                *reinterpret_cast<u16x4*>(
                    &vt[((size_t)(b * H_ * HS + cv)) * T_ + t0]) = pack;
            }
        }
        return;
    }

    const bool doRope = ROPE && (col0 < 2 * C_);
    const bool doScaleQ = ROPE && (col0 < C_);   // pre-scale q for attention

    #pragma unroll
    for (int mi = 0; mi < 4; ++mi) {
        #pragma unroll
        for (int r = 0; r < 4; ++r) {
            const int row = row0 + wr * 64 + mi * 16 + l4 * 4 + r;
            const int t   = row & (T_ - 1);
            #pragma unroll
            for (int nj = 0; nj < 4; ++nj) {
                const int col = col0 + wc * 64 + nj * 16 + l15;
                float v = acc[mi][nj][r] + bv[nj];
                if (doRope) {
                    const float partner = __shfl_xor(v, 1);
                    const float2 sc = tab[t * HALF + ((col & 63) >> 1)];
                    v = v * sc.y + ((col & 1) ? partner : -partner) * sc.x;
                }
                if (doScaleQ) v *= QSCALE;
                if (BF16OUT)
                    ((unsigned short*)Cout)[(size_t)row * N + col] = f2bf(v);
                else
                    ((float*)Cout)[(size_t)row * N + col] = v;
            }
        }
    }
}

// ---------------------------------------------------------------------------
// Flash attention v5 (R10 version, verbatim): 32x32 MFMA, swapped operands,
// PAIRED causal q-tiles, dbuf K/V vmcnt(8), merged 128-j softmax, raw exp2,
// permlane32_swap packing, Q pre-scaled in projection.
// ---------------------------------------------------------------------------
__global__ __launch_bounds__(256, 2) void attn_mfma5_kernel(
    const unsigned short* __restrict__ qkv,   // roped+scaled qkv, bf16
    const unsigned short* __restrict__ vt,    // V^T global [(b*H+h)*64+d][T]
    unsigned short* __restrict__ out)         // [B*T][C] bf16
{
    __shared__ unsigned short Ks[2][128 * 64];   // [j][d], swizzled
    __shared__ unsigned short Vs[2][64 * 128];   // [d][j], swizzled

    const int idx = blockIdx.x;
    const int bh  = idx & 63;                 // b*16 + h
    const int qp  = idx >> 6;                 // 0..7
    const int b   = bh >> 4;
    const int h   = bh & 15;
    const int qtA = qp;
    const int qtB = 15 - qp;

    const int tid  = threadIdx.x;
    const int lane = tid & 63;
    const int w    = tid >> 6;
    const int l31  = lane & 31;
    const int hi   = lane >> 5;

    const int qwA = qtA * 128 + w * 32;
    const int qgA = qwA + l31;
    const int qwB = qtB * 128 + w * 32;
    const int qgB = qwB + l31;

    // Q fragments (pre-scaled by QSCALE in the projection epilogue)
    bf16x8 aqA[4], aqB[4];
    {
        const unsigned short* qpA = &qkv[(size_t)(b * T_ + qgA) * QKV_N + h * HS + hi * 8];
        const unsigned short* qpB = &qkv[(size_t)(b * T_ + qgB) * QKV_N + h * HS + hi * 8];
        #pragma unroll
        for (int kc = 0; kc < 4; ++kc) {
            aqA[kc] = *reinterpret_cast<const bf16x8*>(qpA + kc * 16);
            aqB[kc] = *reinterpret_cast<const bf16x8*>(qpB + kc * 16);
        }
    }

    f32x16 accA0 = {}, accA1 = {}, accB0 = {}, accB1 = {};
    float mA = -INFINITY, lA = 0.f, mB = -INFINITY, lB = 0.f;

    auto stageKV = [&](int buf, int it) {
        #pragma unroll
        for (int n = 0; n < 4; ++n) {
            const int r  = n * 32 + (tid >> 3);
            const int sk = ((tid & 7) ^ (r & 7)) * 8;
            gload16(&qkv[(size_t)(b * T_ + it * 128 + r) * QKV_N + C_ + h * HS + sk],
                    &Ks[buf][(n * 256 + tid) * 8]);
        }
        #pragma unroll
        for (int n = 0; n < 4; ++n) {
            const int d  = n * 16 + (tid >> 4);
            const int sv = ((tid & 15) ^ (d & 7)) * 8;
            gload16(&vt[((size_t)(bh * HS + d)) * T_ + it * 128 + sv],
                    &Vs[buf][(n * 256 + tid) * 8]);
        }
    };

    // merged 128-j processing
    auto process = [&](const unsigned short* Kb, const unsigned short* Vb,
                       const bf16x8* aq, f32x16& a0, f32x16& a1,
                       float& mval, float& lval, int qw, int qg, int kbase) {
        // ---- S^T = K @ Q^T : four 32-j tiles covering 128 j ----
        f32x16 s[4] = {};
        __builtin_amdgcn_s_setprio(1);
        #pragma unroll
        for (int kc = 0; kc < 4; ++kc) {
            const int bo = kc * 32 + hi * 16;          // byte offset in 128B K row
            #pragma unroll
            for (int g = 0; g < 4; ++g) {
                const int rj = g * 32 + l31;
                const bf16x8 ak = *reinterpret_cast<const bf16x8*>(
                    &Kb[rj * 64 + ((bo ^ ((rj & 7) << 4)) >> 1)]);
                s[g] = __builtin_amdgcn_mfma_f32_32x32x16_bf16(ak, aq[kc], s[g], 0, 0, 0);
            }
        }
        __builtin_amdgcn_s_setprio(0);

        // ---- causal mask (Q pre-scaled: s already in log2-exp space) ----
        if (kbase + 127 > qw) {
            #pragma unroll
            for (int g = 0; g < 4; ++g) {
                #pragma unroll
                for (int r = 0; r < 16; ++r) {
                    const int j0 = kbase + g * 32 + (r & 3) + 8 * (r >> 2) + 4 * hi;
                    if (j0 > qg) s[g][r] = -INFINITY;
                }
            }
        }

        // ---- merged online softmax over 128 j, per-lane (q = lane&31) ----
        float tg[4];
        #pragma unroll
        for (int g = 0; g < 4; ++g) {
            const float v0 = FMAX3(s[g][0],  s[g][1],  s[g][2]);
            const float v1 = FMAX3(s[g][3],  s[g][4],  s[g][5]);
            const float v2 = FMAX3(s[g][6],  s[g][7],  s[g][8]);
            const float v3 = FMAX3(s[g][9],  s[g][10], s[g][11]);
            const float v4 = FMAX3(s[g][12], s[g][13], s[g][14]);
            tg[g] = fmaxf(FMAX3(v0, v1, v2), FMAX3(v3, v4, s[g][15]));
        }
        float tm = fmaxf(fmaxf(tg[0], tg[1]), fmaxf(tg[2], tg[3]));
        tm = fmaxf(tm, __shfl_xor(tm, 32));

        const bool upd = (tm > mval + 8.f);          // defer-max THR=8 (log2)
        if (__ballot(upd)) {
            const float nm = upd ? tm : mval;
            const float sf = EXP2(mval - nm);
            lval *= sf;
            #pragma unroll
            for (int r = 0; r < 16; ++r) { a0[r] *= sf; a1[r] *= sf; }
            mval = nm;
        }

        float rs0 = 0.f, rs1 = 0.f, rs2 = 0.f, rs3 = 0.f;
        #pragma unroll
        for (int r = 0; r < 16; ++r) {
            s[0][r] = EXP2(s[0][r] - mval); rs0 += s[0][r];
            s[1][r] = EXP2(s[1][r] - mval); rs1 += s[1][r];
            s[2][r] = EXP2(s[2][r] - mval); rs2 += s[2][r];
            s[3][r] = EXP2(s[3][r] - mval); rs3 += s[3][r];
        }
        float rs = (rs0 + rs1) + (rs2 + rs3);
        rs += __shfl_xor(rs, 32);
        lval += rs;

        // ---- P fragments + PV: O^T += Vt @ P (two 64-j subtiles) ----
        #pragma unroll
        for (int g2 = 0; g2 < 2; ++g2) {
            #pragma unroll
            for (int jt = 0; jt < 2; ++jt) {
                const int g = g2 * 2 + jt;
                #pragma unroll
                for (int c = 0; c < 2; ++c) {
                    const int e = c * 8;
                    const unsigned pa = cvtpk_bf16(s[g][e + 0], s[g][e + 1]);
                    const unsigned pb = cvtpk_bf16(s[g][e + 2], s[g][e + 3]);
                    const unsigned pc = cvtpk_bf16(s[g][e + 4], s[g][e + 5]);
                    const unsigned pd = cvtpk_bf16(s[g][e + 6], s[g][e + 7]);
                    int4 bw;
#if __has_builtin(__builtin_amdgcn_permlane32_swap)
                    const u32x2 rx = __builtin_amdgcn_permlane32_swap(pa, pc, false, false);
                    const u32x2 ry = __builtin_amdgcn_permlane32_swap(pb, pd, false, false);
                    bw.x = (int)rx[0]; bw.y = (int)ry[0];
                    bw.z = (int)rx[1]; bw.w = (int)ry[1];
#else
                    const unsigned pas = (unsigned)__shfl_xor((int)pa, 32);
                    const unsigned pbs = (unsigned)__shfl_xor((int)pb, 32);
                    const unsigned pcs = (unsigned)__shfl_xor((int)pc, 32);
                    const unsigned pds = (unsigned)__shfl_xor((int)pd, 32);
                    bw.x = (int)(hi ? pcs : pa);
                    bw.y = (int)(hi ? pds : pb);
                    bw.z = (int)(hi ? pc  : pas);
                    bw.w = (int)(hi ? pd  : pbs);
#endif
                    const bf16x8 bfrag = __builtin_bit_cast(bf16x8, bw);

                    const int lslot = g2 * 8 + (jt * 2 + c) * 2 + hi;
                    const int d0 = l31;
                    const bf16x8 av0 = *reinterpret_cast<const bf16x8*>(
                        &Vb[d0 * 128 + (lslot ^ (d0 & 7)) * 8]);
                    const int d1 = 32 + l31;
                    const bf16x8 av1 = *reinterpret_cast<const bf16x8*>(
                        &Vb[d1 * 128 + (lslot ^ (d1 & 7)) * 8]);
                    __builtin_amdgcn_s_setprio(1);
                    a0 = __builtin_amdgcn_mfma_f32_32x32x16_bf16(av0, bfrag, a0, 0, 0, 0);
                    a1 = __builtin_amdgcn_mfma_f32_32x32x16_bf16(av1, bfrag, a1, 0, 0, 0);
                    __builtin_amdgcn_s_setprio(0);
                }
            }
        }
    };

    const int nIter = qtB + 1;                       // 128-wide k chunks
    stageKV(0, 0);
    for (int it = 0; it < nIter; ++it) {
        const int cur = it & 1;
        __builtin_amdgcn_sched_barrier(0);
        if (it + 1 < nIter) {
            stageKV(cur ^ 1, it + 1);
            WAIT_VMCNT_8();
        } else {
            WAIT_VMCNT_0();
        }
        __builtin_amdgcn_s_barrier();
        __builtin_amdgcn_sched_barrier(0);

        const unsigned short* Kb = &Ks[cur][0];
        const unsigned short* Vb = &Vs[cur][0];
        const int kbase = it * 128;
        if (kbase <= qwA + 31)
            process(Kb, Vb, aqA, accA0, accA1, mA, lA, qwA, qgA, kbase);
        if (kbase <= qwB + 31)
            process(Kb, Vb, aqB, accB0, accB1, mB, lB, qwB, qgB, kbase);
        __builtin_amdgcn_sched_barrier(0);
        __builtin_amdgcn_s_barrier();
    }

    // ---- write O = acc^T / l ----
    {
        const float inv = 1.0f / lA;
        unsigned short* orow = &out[(size_t)(b * T_ + qgA) * C_ + h * HS];
        #pragma unroll
        for (int g = 0; g < 4; ++g) {
            uint2 wv;
            wv.x = cvtpk_bf16(accA0[4 * g + 0] * inv, accA0[4 * g + 1] * inv);
            wv.y = cvtpk_bf16(accA0[4 * g + 2] * inv, accA0[4 * g + 3] * inv);
            *reinterpret_cast<uint2*>(&orow[8 * g + 4 * hi]) = wv;
            uint2 wv1;
            wv1.x = cvtpk_bf16(accA1[4 * g + 0] * inv, accA1[4 * g + 1] * inv);
            wv1.y = cvtpk_bf16(accA1[4 * g + 2] * inv, accA1[4 * g + 3] * inv);
            *reinterpret_cast<uint2*>(&orow[32 + 8 * g + 4 * hi]) = wv1;
        }
    }
    {
        const float inv = 1.0f / lB;
        unsigned short* orow = &out[(size_t)(b * T_ + qgB) * C_ + h * HS];
        #pragma unroll
        for (int g = 0; g < 4; ++g) {
            uint2 wv;
            wv.x = cvtpk_bf16(accB0[4 * g + 0] * inv, accB0[4 * g + 1] * inv);
            wv.y = cvtpk_bf16(accB0[4 * g + 2] * inv, accB0[4 * g + 3] * inv);
            *reinterpret_cast<uint2*>(&orow[8 * g + 4 * hi]) = wv;
            uint2 wv1;
            wv1.x = cvtpk_bf16(accB1[4 * g + 0] * inv, accB1[4 * g + 1] * inv);
            wv1.y = cvtpk_bf16(accB1[4 * g + 2] * inv, accB1[4 * g + 3] * inv);
            *reinterpret_cast<uint2*>(&orow[32 + 8 * g + 4 * hi]) = wv1;
        }
    }
}

// ---------------------------------------------------------------------------
extern "C" void kernel_launch(void* const* d_in, const int* in_sizes, int n_in,
                              void* d_out, int out_size, void* d_ws, size_t ws_size,
                              hipStream_t stream)
{
    const float* x    = (const float*)d_in[0];   // [B,T,C]
    const float* Wqkv = (const float*)d_in[1];   // [C,3C]
    const float* bqkv = (const float*)d_in[2];   // [3C]
    const float* Wout = (const float*)d_in[3];   // [C,C]
    const float* bout = (const float*)d_in[4];   // [C]
    float* out = (float*)d_out;                  // [B,T,C] fp32

    char* ws = (char*)d_ws;
    unsigned short* qkvb  = (unsigned short*)ws;                       // 50,331,648
    unsigned short* xb    = (unsigned short*)(ws + 50331648);          // 16,777,216
    unsigned short* attnb = (unsigned short*)(ws + 67108864);          // 16,777,216
    unsigned short* vt_g  = (unsigned short*)(ws + 83886080);          // 16,777,216
    unsigned short* Wqkvt = (unsigned short*)(ws + 100663296);         //  6,291,456
    unsigned short* Woutt = (unsigned short*)(ws + 106954752);         //  2,097,152
    float2* tab           = (float2*)(ws + 109051904);                 //    524,288

    // 1) fused prep: x cast + rope table + both weight transposes
    prep2_kernel<<<8448, 256, 0, stream>>>(x, xb, tab, Wqkv, Wout, Wqkvt, Woutt);

    // 2) QKV projection, fused RoPE + Q-prescale (q,k cols) + fused V^T (v cols)
    gemm_mfma_kernel<QKV_N, C_, true, true, true>
        <<<(M_ / 128) * (QKV_N / 128), 256, 0, stream>>>(
        xb, Wqkvt, bqkv, tab, qkvb, vt_g, QKV_N / 128, M_ / 128);

    // 3) attention -> attnb [B,T,C] bf16 (paired causal q-tiles, merged softmax)
    attn_mfma5_kernel<<<B_ * H_ * (T_ / 256), 256, 0, stream>>>(qkvb, vt_g, attnb);

    // 4) output projection (fp32 out): 64 x 8 = 512 blocks, XCD-region map
    gemm_mfma_kernel<C_, C_, false, false, false>
        <<<(M_ / 128) * (C_ / 128), 256, 0, stream>>>(
        attnb, Woutt, bout, nullptr, out, nullptr, C_ / 128, M_ / 128);
}